// Round 3
// baseline (6544.969 us; speedup 1.0000x reference)
//
#include <hip/hip_runtime.h>
#include <math.h>
#include <stdint.h>

// ReLSTM_18940805775611 — B=512, T=128, H=512, 2-layer LSTM, 128 TF + 127 AR.
// R21 (4176.9us): persistent kernel, MALL-coherent flag sync — proved the wall
// is NOT launch overhead: 16.7us/step at 1 wave/SIMD, MfmaUtil 8%, 2.5e8 LDS
// bank-conflict cycles. Critical path = 12 sequential LDS-staging iterations
// per step (bypass-load ~700cy each, nothing to hide them) + c1/c2 L2 traffic.
// R22: remove ALL per-step staging.
//  - Weights LDS-RESIDENT in MFMA-fragment order, filled once (wb0 64KB +
//    wb1i 64KB = 128KB). Only wb1h streams from L2 (direct fragment loads).
//  - A (h state) loaded directly as MFMA fragments from MALL (sc0 sc1),
//    all loads issued at once -> ONE latency exposure per layer (was 4-8).
//  - c1/c2 in REGISTERS (4+4 cells/thread) -> no per-step c traffic at all.
//  - 512 threads (2 waves/SIMD): waves 0-3 / 4-7 split each layer's K-range
//    (L0: ks 0-7 / 8-15; L1: h1*wb1i / h2*wb1h), partials combined via padded
//    LDS accsh. Halves each wave's chain, doubles latency-hiding.
//  - Flag/ping-pong/poll/parts protocol IDENTICAL to proven R21 (WAR cases
//    re-derived: flagA(t) / flagB(t-1) waits cover every buffer overwrite).
// LDS: 64+64+20+4.3+0.25 = ~153KB, 1 block/CU, 256 blocks.

namespace {
constexpr int NH  = 512;    // hidden
constexpr int NT  = 128;    // seq len
constexpr int NB  = 512;    // batch
}

typedef __attribute__((ext_vector_type(8))) short bf16x8;
typedef __attribute__((ext_vector_type(4))) float f32x4;
typedef __attribute__((ext_vector_type(4))) unsigned int u32x4;

// Present in case the harness resolves this symbol.
__global__ void ReLSTM_18940805775611_kernel() {}

__device__ __forceinline__ unsigned short lstm9_f2b(float f) {
    union { float f; uint32_t i; } v; v.f = f;
    const uint32_t r = v.i + 0x7FFFu + ((v.i >> 16) & 1u);   // RNE
    return (unsigned short)(r >> 16);
}
__device__ __forceinline__ float lstm9_sig(float x) {
    return 1.0f / (1.0f + expf(-x));
}

// ---- sentinel: truncation diagnostic ----
__global__ void lstm9_mark(float* out) {
    const int i = blockIdx.x * blockDim.x + threadIdx.x;
    if (i < NB * NT) out[i] = 2.03125f;
}

// ---- one-time prep: weights fp32->bf16 (RNE), summed biases, zero states,
// zero flags ----
__global__ void lstm9_prep(
    const float* whh0, const float* wih1, const float* whh1,
    const float* bih0, const float* bhh0, const float* bih1, const float* bhh1,
    unsigned short* wb0, unsigned short* wb1i, unsigned short* wb1h,
    float* bsum0, float* bsum1,
    unsigned short* hz, int* flags)
{
    const size_t stride = (size_t)gridDim.x * blockDim.x;
    const size_t i0 = (size_t)blockIdx.x * blockDim.x + threadIdx.x;
    const size_t NW = (size_t)4 * NH * NH;
    for (size_t i = i0; i < NW; i += stride) {
        wb0 [i] = lstm9_f2b(whh0[i]);
        wb1i[i] = lstm9_f2b(wih1[i]);
        wb1h[i] = lstm9_f2b(whh1[i]);
    }
    for (size_t i = i0; i < (size_t)4 * NH; i += stride) {
        bsum0[i] = bih0[i] + bhh0[i];
        bsum1[i] = bih1[i] + bhh1[i];
    }
    for (size_t i = i0; i < (size_t)4 * NB * NH; i += stride) hz[i] = 0;
    for (size_t i = i0; i < (size_t)2 * 256 * 8 * 32; i += stride) flags[i] = 0;
}

// ---- asm memory helpers (sc0 sc1 = bypass L1+L2, coherent at MALL) ----
__device__ __forceinline__ void lstm9_ldA(u32x4& d, const unsigned short* p) {
    asm volatile("global_load_dwordx4 %0, %1, off sc0 sc1" : "=v"(d) : "v"(p));
}
__device__ __forceinline__ void lstm9_ldB(u32x4& d, const unsigned short* p) {
    asm volatile("global_load_dwordx4 %0, %1, off" : "=v"(d) : "v"(p));
}
__device__ __forceinline__ void lstm9_ldP(u32x4& d, const float* p) {
    asm volatile("global_load_dwordx4 %0, %1, off sc0 sc1" : "=v"(d) : "v"(p));
}
#define LSTM9_WAIT8(a,b,c,d,e,f,g,h) \
    asm volatile("s_waitcnt vmcnt(0)" \
        : "+v"(a),"+v"(b),"+v"(c),"+v"(d),"+v"(e),"+v"(f),"+v"(g),"+v"(h) :: "memory")
#define LSTM9_WAIT2(a,b) \
    asm volatile("s_waitcnt vmcnt(0)" : "+v"(a),"+v"(b) :: "memory")
__device__ __forceinline__ void lstm9_stH(unsigned short* p, unsigned short v) {
    unsigned int x = v;
    asm volatile("global_store_short %0, %1, off sc0 sc1" :: "v"(p), "v"(x) : "memory");
}
__device__ __forceinline__ void lstm9_stF(float* p, float v) {
    asm volatile("global_store_dword %0, %1, off sc0 sc1" :: "v"(p), "v"(v) : "memory");
}
__device__ __forceinline__ void lstm9_stI(int* p, int v) {
    asm volatile("global_store_dword %0, %1, off sc0 sc1" :: "v"(p), "v"(v) : "memory");
}
__device__ __forceinline__ void lstm9_drain() {
    asm volatile("s_waitcnt vmcnt(0)" ::: "memory");
}

// ---- group barrier: wait until all 32 flag slots of this group are set ----
__device__ __forceinline__ void lstm9_waitgrp(const int* base) {
    if (threadIdx.x < 64) {
        const int sl = (int)threadIdx.x & 31;
        for (;;) {
            int f;
            asm volatile("global_load_dword %0, %1, off sc0 sc1\n\t"
                         "s_waitcnt vmcnt(0)"
                         : "=v"(f) : "v"(base + sl) : "memory");
            if (__all(f != 0)) break;
            __builtin_amdgcn_s_sleep(2);
        }
    }
    __syncthreads();
}

#define BFR(Barr, gt, kk) (*(const bf16x8*)&Barr[gt][kk][lane][0])

// ---- the persistent kernel: all 255 steps (128 TF + 127 AR) ----
__global__ __launch_bounds__(512, 2) void lstm9_persist(
    const float* __restrict__ xin, float* __restrict__ outf,
    const unsigned short* __restrict__ wb0,
    const unsigned short* __restrict__ wb1i,
    const unsigned short* __restrict__ wb1h,
    const float* __restrict__ bsum0, const float* __restrict__ bsum1,
    const float* __restrict__ wih0f, const float* __restrict__ wlinf,
    const float* __restrict__ blinf,
    unsigned short* h1a, unsigned short* h1b,
    unsigned short* h2a, unsigned short* h2b,
    float* parts, int* flags)
{
    __shared__ unsigned short Bsh0[4][16][64][8];   // w_hh0, fragment order, 64KB
    __shared__ unsigned short Bsh1[4][16][64][8];   // w_ih1, fragment order, 64KB
    __shared__ float accsh[4][64][20];              // K-split partial accs (padded)
    __shared__ float redsh[64][17];
    __shared__ float ysh[64];

    const int tid  = threadIdx.x;
    const int lane = tid & 63;
    const int w    = tid >> 6;        // 0..7
    const int wl4  = w & 3;           // m-tile 0..3 (16 rows each)
    const int hi   = w >> 2;          // 0 = low half, 1 = high half (K-split)
    const int quad = lane >> 4;
    const int ln15 = lane & 15;
    const int bid  = blockIdx.x;
    const int jt = (bid & 7) * 4 + ((bid >> 3) & 3);  // j-tile 0..31 (XCD spread)
    const int g  = bid >> 5;                          // m-group 0..7
    const int j0 = jt * 16;
    const int m0 = g * 64;
    const int rowA = m0 + wl4 * 16 + ln15;            // A-fragment row
    const int mb   = m0 + wl4 * 16 + quad * 4;        // epilogue row base
    const int jv   = j0 + ln15;

    // ---- one-time: weights into LDS in MFMA-fragment order ----
    for (int idx = tid; idx < 4 * 16 * 64; idx += 512) {
        const int gt = idx >> 10;
        const int ks = (idx >> 6) & 15;
        const int l  = idx & 63;
        const int row = l & 15, q = l >> 4;
        const size_t go = ((size_t)(gt * NH + j0 + row)) * NH + ks * 32 + q * 8;
        *(uint4*)&Bsh0[gt][ks][l][0] = *(const uint4*)(wb0  + go);
        *(uint4*)&Bsh1[gt][ks][l][0] = *(const uint4*)(wb1i + go);
    }
    __syncthreads();

    // step-invariant scalars
    const float b0i = bsum0[jv],          b0f = bsum0[NH + jv];
    const float b0g = bsum0[2 * NH + jv], b0o = bsum0[3 * NH + jv];
    const float wxi = wih0f[jv],          wxf = wih0f[NH + jv];
    const float wxg = wih0f[2 * NH + jv], wxo = wih0f[3 * NH + jv];
    const float b1i = bsum1[jv],          b1f = bsum1[NH + jv];
    const float b1g = bsum1[2 * NH + jv], b1o = bsum1[3 * NH + jv];
    const float wl_ = wlinf[jv];
    const float bl_ = blinf[0];

    float c1r[4] = {0.f, 0.f, 0.f, 0.f};
    float c2r[4] = {0.f, 0.f, 0.f, 0.f};

    unsigned short* h1p[2] = { h1a, h1b };
    unsigned short* h2p[2] = { h2a, h2b };
    int* flagA = flags;
    int* flagB = flags + 256 * 8 * 32;

    for (int t = 0; t < 256; ++t) {
        const unsigned short* h1rd = h1p[t & 1];
        unsigned short*       h1wr = h1p[(t + 1) & 1];
        const unsigned short* h2rd = h2p[t & 1];
        unsigned short*       h2wr = h2p[(t + 1) & 1];

        float xv[4] = {0.f, 0.f, 0.f, 0.f};
        if (t < 128) {
            if (!hi) {
                #pragma unroll
                for (int r = 0; r < 4; ++r)
                    xv[r] = xin[(size_t)(mb + r) * NT + t];
            }
        } else {
            // y(t-128) = bl + sum_j partials(t-1); covered by flagB(t-1)
            lstm9_waitgrp(flagB + ((t - 1) * 8 + g) * 32);
            const float* pslot = parts + (size_t)((t - 1) & 1) * NB * 32;
            if (tid < 256) {
                const int row = tid >> 2, q = tid & 3;
                u32x4 v0, v1;
                lstm9_ldP(v0, pslot + (size_t)(m0 + row) * 32 + q * 8);
                lstm9_ldP(v1, pslot + (size_t)(m0 + row) * 32 + q * 8 + 4);
                LSTM9_WAIT2(v0, v1);
                const float* f0 = (const float*)&v0;
                const float* f1 = (const float*)&v1;
                redsh[row][q] = f0[0] + f0[1] + f0[2] + f0[3]
                              + f1[0] + f1[1] + f1[2] + f1[3];
            }
            __syncthreads();
            if (tid < 64) {
                const float y = bl_ + redsh[tid][0] + redsh[tid][1]
                                    + redsh[tid][2] + redsh[tid][3];
                ysh[tid] = y;
                if (jt == 0)
                    outf[(size_t)(m0 + tid) * NT + (t - 128)] = y;
            }
            __syncthreads();
            if (t == 255) break;   // last y published; done
            if (!hi) {
                #pragma unroll
                for (int r = 0; r < 4; ++r)
                    xv[r] = ysh[wl4 * 16 + quad * 4 + r];
            }
        }

        // ---- layer 0: gates = x*w_ih0 + h1(t-1) @ w_hh0^T + bsum0 ----
        // K-split: low waves ks 0..7, high waves ks 8..15. One load wait total.
        f32x4 a0 = {0.f, 0.f, 0.f, 0.f};
        f32x4 a1 = a0, a2 = a0, a3 = a0;
        {
            const int ksb = hi * 8;
            u32x4 rA[8];
            #pragma unroll
            for (int ks = 0; ks < 8; ++ks)
                lstm9_ldA(rA[ks], h1rd + (size_t)rowA * NH + (ksb + ks) * 32 + quad * 8);
            LSTM9_WAIT8(rA[0], rA[1], rA[2], rA[3], rA[4], rA[5], rA[6], rA[7]);
            __builtin_amdgcn_sched_barrier(0);
            #pragma unroll
            for (int ks = 0; ks < 8; ++ks) {
                const bf16x8 af = *(const bf16x8*)&rA[ks];
                const int kk = ksb + ks;
                a0 = __builtin_amdgcn_mfma_f32_16x16x32_bf16(af, BFR(Bsh0, 0, kk), a0, 0, 0, 0);
                a1 = __builtin_amdgcn_mfma_f32_16x16x32_bf16(af, BFR(Bsh0, 1, kk), a1, 0, 0, 0);
                a2 = __builtin_amdgcn_mfma_f32_16x16x32_bf16(af, BFR(Bsh0, 2, kk), a2, 0, 0, 0);
                a3 = __builtin_amdgcn_mfma_f32_16x16x32_bf16(af, BFR(Bsh0, 3, kk), a3, 0, 0, 0);
            }
        }
        if (hi) {
            *(f32x4*)&accsh[wl4][lane][0]  = a0;
            *(f32x4*)&accsh[wl4][lane][4]  = a1;
            *(f32x4*)&accsh[wl4][lane][8]  = a2;
            *(f32x4*)&accsh[wl4][lane][12] = a3;
        }
        __syncthreads();
        if (!hi) {
            a0 += *(const f32x4*)&accsh[wl4][lane][0];
            a1 += *(const f32x4*)&accsh[wl4][lane][4];
            a2 += *(const f32x4*)&accsh[wl4][lane][8];
            a3 += *(const f32x4*)&accsh[wl4][lane][12];
            #pragma unroll
            for (int r = 0; r < 4; ++r) {
                const float gi = a0[r] + fmaf(xv[r], wxi, b0i);
                const float gf = a1[r] + fmaf(xv[r], wxf, b0f);
                const float gg = a2[r] + fmaf(xv[r], wxg, b0g);
                const float go = a3[r] + fmaf(xv[r], wxo, b0o);
                float cv = c1r[r];
                cv = lstm9_sig(gf) * cv + lstm9_sig(gi) * tanhf(gg);
                c1r[r] = cv;
                lstm9_stH(h1wr + (size_t)(mb + r) * NH + jv,
                          lstm9_f2b(lstm9_sig(go) * tanhf(cv)));
            }
        }
        lstm9_drain();
        __syncthreads();
        if (tid == 0) lstm9_stI(flagA + (t * 8 + g) * 32 + jt, 1);
        lstm9_waitgrp(flagA + (t * 8 + g) * 32);           // h1(t) all-j ready
        if (t >= 1 && t < 128)
            lstm9_waitgrp(flagB + ((t - 1) * 8 + g) * 32); // h2(t-1) ready (TF)

        // ---- layer 1: gates = h1(t) @ w_ih1^T + h2(t-1) @ w_hh1^T + bsum1 ----
        // K-split: low waves = h1*wb1i (LDS-resident B), high = h2*wb1h (streamed).
        a0 = {0.f, 0.f, 0.f, 0.f}; a1 = a0; a2 = a0; a3 = a0;
        if (!hi) {
            u32x4 rA[16];
            #pragma unroll
            for (int ks = 0; ks < 16; ++ks)
                lstm9_ldA(rA[ks], h1wr + (size_t)rowA * NH + ks * 32 + quad * 8);
            LSTM9_WAIT8(rA[0], rA[1], rA[2], rA[3], rA[4], rA[5], rA[6], rA[7]);
            LSTM9_WAIT8(rA[8], rA[9], rA[10], rA[11], rA[12], rA[13], rA[14], rA[15]);
            __builtin_amdgcn_sched_barrier(0);
            #pragma unroll
            for (int ks = 0; ks < 16; ++ks) {
                const bf16x8 af = *(const bf16x8*)&rA[ks];
                a0 = __builtin_amdgcn_mfma_f32_16x16x32_bf16(af, BFR(Bsh1, 0, ks), a0, 0, 0, 0);
                a1 = __builtin_amdgcn_mfma_f32_16x16x32_bf16(af, BFR(Bsh1, 1, ks), a1, 0, 0, 0);
                a2 = __builtin_amdgcn_mfma_f32_16x16x32_bf16(af, BFR(Bsh1, 2, ks), a2, 0, 0, 0);
                a3 = __builtin_amdgcn_mfma_f32_16x16x32_bf16(af, BFR(Bsh1, 3, ks), a3, 0, 0, 0);
            }
        } else {
            u32x4 rA[16];
            #pragma unroll
            for (int ks = 0; ks < 16; ++ks)
                lstm9_ldA(rA[ks], h2rd + (size_t)rowA * NH + ks * 32 + quad * 8);
            u32x4 wh[16];
            #pragma unroll
            for (int c4 = 0; c4 < 4; ++c4) {
                #pragma unroll
                for (int kk = 0; kk < 4; ++kk) {
                    const int ks = c4 * 4 + kk;
                    #pragma unroll
                    for (int gt = 0; gt < 4; ++gt)
                        lstm9_ldB(wh[kk * 4 + gt],
                                  wb1h + ((size_t)(gt * NH + j0 + ln15)) * NH
                                       + ks * 32 + quad * 8);
                }
                LSTM9_WAIT8(wh[0], wh[1], wh[2], wh[3], wh[4], wh[5], wh[6], wh[7]);
                LSTM9_WAIT8(wh[8], wh[9], wh[10], wh[11], wh[12], wh[13], wh[14], wh[15]);
                __builtin_amdgcn_sched_barrier(0);
                #pragma unroll
                for (int kk = 0; kk < 4; ++kk) {
                    const int ks = c4 * 4 + kk;
                    const bf16x8 af = *(const bf16x8*)&rA[ks];
                    a0 = __builtin_amdgcn_mfma_f32_16x16x32_bf16(af, *(const bf16x8*)&wh[kk * 4 + 0], a0, 0, 0, 0);
                    a1 = __builtin_amdgcn_mfma_f32_16x16x32_bf16(af, *(const bf16x8*)&wh[kk * 4 + 1], a1, 0, 0, 0);
                    a2 = __builtin_amdgcn_mfma_f32_16x16x32_bf16(af, *(const bf16x8*)&wh[kk * 4 + 2], a2, 0, 0, 0);
                    a3 = __builtin_amdgcn_mfma_f32_16x16x32_bf16(af, *(const bf16x8*)&wh[kk * 4 + 3], a3, 0, 0, 0);
                }
            }
        }
        if (hi) {
            *(f32x4*)&accsh[wl4][lane][0]  = a0;
            *(f32x4*)&accsh[wl4][lane][4]  = a1;
            *(f32x4*)&accsh[wl4][lane][8]  = a2;
            *(f32x4*)&accsh[wl4][lane][12] = a3;
        }
        __syncthreads();
        if (!hi) {
            a0 += *(const f32x4*)&accsh[wl4][lane][0];
            a1 += *(const f32x4*)&accsh[wl4][lane][4];
            a2 += *(const f32x4*)&accsh[wl4][lane][8];
            a3 += *(const f32x4*)&accsh[wl4][lane][12];
            float hv[4], cva[4];
            #pragma unroll
            for (int r = 0; r < 4; ++r) {
                const float gi = a0[r] + b1i;
                const float gf = a1[r] + b1f;
                const float gg = a2[r] + b1g;
                const float go = a3[r] + b1o;
                float cv = c2r[r];
                cv = lstm9_sig(gf) * cv + lstm9_sig(gi) * tanhf(gg);
                c2r[r] = cv;
                cva[r] = cv;
                hv[r] = lstm9_sig(go) * tanhf(cv);
                lstm9_stH(h2wr + (size_t)(mb + r) * NH + jv, lstm9_f2b(hv[r]));
            }
            if (t >= 127) {
                // partial dot for y(t-127): t==127 uses CELL state (ref quirk)
                #pragma unroll
                for (int r = 0; r < 4; ++r)
                    redsh[wl4 * 16 + quad * 4 + r][ln15] =
                        (t == 127 ? cva[r] : hv[r]) * wl_;
            }
        }
        if (t >= 127) {
            __syncthreads();
            if (tid < 64) {
                float s = 0.0f;
                #pragma unroll
                for (int j = 0; j < 16; ++j) s += redsh[tid][j];
                lstm9_stF(parts + (size_t)(t & 1) * NB * 32
                                + (size_t)(m0 + tid) * 32 + jt, s);
            }
        }
        lstm9_drain();
        __syncthreads();
        if (tid == 0) lstm9_stI(flagB + (t * 8 + g) * 32 + jt, 1);
    }
}

extern "C" void kernel_launch(void* const* d_in, const int* in_sizes, int n_in,
                              void* d_out, int out_size, void* d_ws, size_t ws_size,
                              hipStream_t stream)
{
    int base = 3;
    if (!(n_in > 3 && in_sizes[3] == 4 * NH)) {
        for (int i = 1; i + 9 < n_in; ++i)
            if (in_sizes[i] == 4 * NH) { base = i; break; }
    }
    const float* xin  = (const float*)d_in[0];
    const float* wih0 = (const float*)d_in[base + 0];
    const float* whh0 = (const float*)d_in[base + 1];
    const float* bih0 = (const float*)d_in[base + 2];
    const float* bhh0 = (const float*)d_in[base + 3];
    const float* wih1 = (const float*)d_in[base + 4];
    const float* whh1 = (const float*)d_in[base + 5];
    const float* bih1 = (const float*)d_in[base + 6];
    const float* bhh1 = (const float*)d_in[base + 7];
    const float* wlin = (const float*)d_in[base + 8];
    const float* blin = (const float*)d_in[base + 9];
    float* outf = (float*)d_out;

    // ws layout (~9 MB): bf16 weights | bf16 h ping-pong | fp32 bias |
    // y-partials | flags.
    const size_t NW = (size_t)4 * NH * NH;
    const size_t S  = (size_t)NB * NH;
    unsigned short* wb0  = (unsigned short*)d_ws;
    unsigned short* wb1i = wb0 + NW;
    unsigned short* wb1h = wb1i + NW;
    unsigned short* h1b0 = wb1h + NW;
    unsigned short* h1b1 = h1b0 + S;
    unsigned short* h2b0 = h1b1 + S;
    unsigned short* h2b1 = h2b0 + S;
    float* bsum0 = (float*)(h2b1 + S);
    float* bsum1 = bsum0 + 4 * NH;
    float* parts = bsum1 + 4 * NH;               // 2 slots x 512 m x 32 j
    int*   flags = (int*)(parts + 2 * NB * 32);  // flagA | flagB

    lstm9_mark<<<(NB * NT + 255) / 256, 256, 0, stream>>>(outf);
    lstm9_prep<<<1024, 256, 0, stream>>>(whh0, wih1, whh1, bih0, bhh0, bih1, bhh1,
                                         wb0, wb1i, wb1h, bsum0, bsum1,
                                         h1b0, flags);
    lstm9_persist<<<256, 512, 0, stream>>>(xin, outf, wb0, wb1i, wb1h,
                                           bsum0, bsum1, wih0, wlin, blin,
                                           h1b0, h1b1, h2b0, h2b1,
                                           parts, flags);
}

// Round 4
// 3629.074 us; speedup vs baseline: 1.8035x; 1.8035x over previous
//
#include <hip/hip_runtime.h>
#include <math.h>
#include <stdint.h>

// ReLSTM_18940805775611 — B=512, T=128, H=512, 2-layer LSTM, 128 TF + 127 AR.
// R21 (4176.9us): persistent, flag sync via MALL; latency-bound (12 staging
// exposures/step + 2.5e8 LDS conflicts). R22 (6544.9us REGRESSION): killed
// conflicts (1.3e6) but put wb1h L2-streaming serially on the critical path
// (4 chunked vmcnt(0) exposures) + K-split accsh barriers + 2 back-to-back
// waitgrps. R23 = R22's good parts, restructured:
//  - 256 threads / 4 waves / 1 wave/SIMD -> 512-VGPR budget: wb1h ENTIRELY in
//    256 VGPRs/lane (loaded once). Layer-1 h2-part = pure register MFMAs.
//    Nothing streams from L2 in the t-loop. No K-split, no accsh.
//  - wb0 + wb1i LDS-resident in MFMA-fragment order (128KB, verified in R22).
//  - ONE merged poll per TF step (lanes 0-31 flagA(t), 32-63 flagB(t-1)).
//  - A-loads software-pipelined with register-tied s_waitcnt vmcnt(8): issue
//    8+8, wait-to-8, MFMA while next batch flies (ping/pong reg batches).
//    All loop loads are asm volatile + "memory" so vmcnt counts stay exact.
//  - AR: L0 A-loads issue BEFORE the flagB poll (fly during it); x is a
//    rank-1 update applied in the epilogue after y(t-1) is reduced.
//  - c1/c2 in registers; flag protocol / ping-pong / parts identical to the
//    R21/R22-verified scheme (WAR cases re-derived, all covered).
// LDS ~133KB (1 block/CU); 256 blocks = 256 CUs.

namespace {
constexpr int NH  = 512;    // hidden
constexpr int NT  = 128;    // seq len
constexpr int NB  = 512;    // batch
}

typedef __attribute__((ext_vector_type(8))) short bf16x8;
typedef __attribute__((ext_vector_type(4))) float f32x4;
typedef __attribute__((ext_vector_type(4))) unsigned int u32x4;

// Present in case the harness resolves this symbol.
__global__ void ReLSTM_18940805775611_kernel() {}

__device__ __forceinline__ unsigned short lstm9_f2b(float f) {
    union { float f; uint32_t i; } v; v.f = f;
    const uint32_t r = v.i + 0x7FFFu + ((v.i >> 16) & 1u);   // RNE
    return (unsigned short)(r >> 16);
}
__device__ __forceinline__ float lstm9_sig(float x) {
    return 1.0f / (1.0f + expf(-x));
}

// ---- sentinel: truncation diagnostic ----
__global__ void lstm9_mark(float* out) {
    const int i = blockIdx.x * blockDim.x + threadIdx.x;
    if (i < NB * NT) out[i] = 2.03125f;
}

// ---- one-time prep: weights fp32->bf16 (RNE), summed biases, zero states,
// zero flags ----
__global__ void lstm9_prep(
    const float* whh0, const float* wih1, const float* whh1,
    const float* bih0, const float* bhh0, const float* bih1, const float* bhh1,
    unsigned short* wb0, unsigned short* wb1i, unsigned short* wb1h,
    float* bsum0, float* bsum1,
    unsigned short* hz, int* flags)
{
    const size_t stride = (size_t)gridDim.x * blockDim.x;
    const size_t i0 = (size_t)blockIdx.x * blockDim.x + threadIdx.x;
    const size_t NW = (size_t)4 * NH * NH;
    for (size_t i = i0; i < NW; i += stride) {
        wb0 [i] = lstm9_f2b(whh0[i]);
        wb1i[i] = lstm9_f2b(wih1[i]);
        wb1h[i] = lstm9_f2b(whh1[i]);
    }
    for (size_t i = i0; i < (size_t)4 * NH; i += stride) {
        bsum0[i] = bih0[i] + bhh0[i];
        bsum1[i] = bih1[i] + bhh1[i];
    }
    for (size_t i = i0; i < (size_t)4 * NB * NH; i += stride) hz[i] = 0;
    for (size_t i = i0; i < (size_t)2 * 256 * 8 * 32; i += stride) flags[i] = 0;
}

// ---- asm memory helpers (sc0 sc1 = bypass L1+L2, coherent at MALL) ----
__device__ __forceinline__ void lstm9_ldA(u32x4& d, const unsigned short* p) {
    asm volatile("global_load_dwordx4 %0, %1, off sc0 sc1"
                 : "=v"(d) : "v"(p) : "memory");
}
__device__ __forceinline__ void lstm9_ldP(u32x4& d, const float* p) {
    asm volatile("global_load_dwordx4 %0, %1, off sc0 sc1"
                 : "=v"(d) : "v"(p) : "memory");
}
#define LSTM9_W8(N, a,b,c,d,e,f,g,h) \
    asm volatile("s_waitcnt vmcnt(" #N ")" \
        : "+v"(a),"+v"(b),"+v"(c),"+v"(d),"+v"(e),"+v"(f),"+v"(g),"+v"(h) :: "memory")
#define LSTM9_WAIT2(a,b) \
    asm volatile("s_waitcnt vmcnt(0)" : "+v"(a),"+v"(b) :: "memory")
__device__ __forceinline__ void lstm9_stH(unsigned short* p, unsigned short v) {
    unsigned int x = v;
    asm volatile("global_store_short %0, %1, off sc0 sc1" :: "v"(p), "v"(x) : "memory");
}
__device__ __forceinline__ void lstm9_stF(float* p, float v) {
    asm volatile("global_store_dword %0, %1, off sc0 sc1" :: "v"(p), "v"(v) : "memory");
}
__device__ __forceinline__ void lstm9_stI(int* p, int v) {
    asm volatile("global_store_dword %0, %1, off sc0 sc1" :: "v"(p), "v"(v) : "memory");
}
__device__ __forceinline__ void lstm9_drain() {
    asm volatile("s_waitcnt vmcnt(0)" ::: "memory");
}

// ---- group barriers: wait until all 32 flag slots of a group are set ----
__device__ __forceinline__ void lstm9_waitgrp(const int* base) {
    if (threadIdx.x < 64) {
        const int sl = (int)threadIdx.x & 31;
        for (;;) {
            int f;
            asm volatile("global_load_dword %0, %1, off sc0 sc1\n\t"
                         "s_waitcnt vmcnt(0)"
                         : "=v"(f) : "v"(base + sl) : "memory");
            if (__all(f != 0)) break;
            __builtin_amdgcn_s_sleep(2);
        }
    }
    __syncthreads();
}
// merged: lanes 0-31 poll baseA, lanes 32-63 poll baseB (one round trip)
__device__ __forceinline__ void lstm9_waitgrp2(const int* baseA, const int* baseB) {
    if (threadIdx.x < 64) {
        const int sl = (int)threadIdx.x & 31;
        const int* p = ((threadIdx.x < 32) ? baseA : baseB) + sl;
        for (;;) {
            int f;
            asm volatile("global_load_dword %0, %1, off sc0 sc1\n\t"
                         "s_waitcnt vmcnt(0)"
                         : "=v"(f) : "v"(p) : "memory");
            if (__all(f != 0)) break;
            __builtin_amdgcn_s_sleep(2);
        }
    }
    __syncthreads();
}

#define BFR0(gt, kk) (*(const bf16x8*)&Bsh0[gt][kk][lane][0])
#define BFR1(gt, kk) (*(const bf16x8*)&Bsh1[gt][kk][lane][0])
#define WHR(gt, kk)  (*(const bf16x8*)&whr[(gt) * 16 + (kk)])

// ---- the persistent kernel: all 255 steps (128 TF + 127 AR) ----
__global__ __launch_bounds__(256, 1) void lstm9_persist(
    const float* __restrict__ xin, float* __restrict__ outf,
    const unsigned short* __restrict__ wb0,
    const unsigned short* __restrict__ wb1i,
    const unsigned short* __restrict__ wb1h,
    const float* __restrict__ bsum0, const float* __restrict__ bsum1,
    const float* __restrict__ wih0f, const float* __restrict__ wlinf,
    const float* __restrict__ blinf,
    unsigned short* h1a, unsigned short* h1b,
    unsigned short* h2a, unsigned short* h2b,
    float* parts, int* flags)
{
    __shared__ unsigned short Bsh0[4][16][64][8];   // w_hh0 fragments, 64KB
    __shared__ unsigned short Bsh1[4][16][64][8];   // w_ih1 fragments, 64KB
    __shared__ float redsh[64][17];
    __shared__ float ysh[64];

    const int tid  = threadIdx.x;
    const int lane = tid & 63;
    const int wv   = tid >> 6;        // 0..3 -> m-subtile (16 rows each)
    const int quad = lane >> 4;
    const int ln15 = lane & 15;
    const int bid  = blockIdx.x;
    const int jt = (bid & 7) * 4 + ((bid >> 3) & 3);  // j-tile 0..31 (XCD spread)
    const int g  = bid >> 5;                          // m-group 0..7
    const int j0 = jt * 16;
    const int m0 = g * 64;
    const int rowA = m0 + wv * 16 + ln15;             // A-fragment row
    const int mb   = m0 + wv * 16 + quad * 4;         // epilogue row base
    const int jv   = j0 + ln15;

    // ---- one-time: wb0/wb1i into LDS in fragment order (verified in R22) ----
    for (int idx = tid; idx < 4 * 16 * 64; idx += 256) {
        const int gt = idx >> 10;
        const int ks = (idx >> 6) & 15;
        const int l  = idx & 63;
        const int row = l & 15, q = l >> 4;
        const size_t go = ((size_t)(gt * NH + j0 + row)) * NH + ks * 32 + q * 8;
        *(u32x4*)&Bsh0[gt][ks][l][0] = *(const u32x4*)(wb0  + go);
        *(u32x4*)&Bsh1[gt][ks][l][0] = *(const u32x4*)(wb1i + go);
    }
    // ---- one-time: wb1h fragments into 256 VGPRs/lane ----
    u32x4 whr[64];
    #pragma unroll
    for (int gt = 0; gt < 4; ++gt) {
        #pragma unroll
        for (int ks = 0; ks < 16; ++ks)
            whr[gt * 16 + ks] = *(const u32x4*)(
                wb1h + ((size_t)(gt * NH + j0 + ln15)) * NH + ks * 32 + quad * 8);
    }
    __syncthreads();

    // step-invariant scalars
    const float b0i = bsum0[jv],          b0f = bsum0[NH + jv];
    const float b0g = bsum0[2 * NH + jv], b0o = bsum0[3 * NH + jv];
    const float wxi = wih0f[jv],          wxf = wih0f[NH + jv];
    const float wxg = wih0f[2 * NH + jv], wxo = wih0f[3 * NH + jv];
    const float b1i = bsum1[jv],          b1f = bsum1[NH + jv];
    const float b1g = bsum1[2 * NH + jv], b1o = bsum1[3 * NH + jv];
    const float wl_ = wlinf[jv];
    const float bl_ = blinf[0];

    float c1r[4] = {0.f, 0.f, 0.f, 0.f};
    float c2r[4] = {0.f, 0.f, 0.f, 0.f};

    unsigned short* h1p[2] = { h1a, h1b };
    unsigned short* h2p[2] = { h2a, h2b };
    int* flagA = flags;
    int* flagB = flags + 256 * 8 * 32;

    u32x4 rP[8], rQ[8];

    for (int t = 0; t < 256; ++t) {
        const unsigned short* h1rd = h1p[t & 1];
        unsigned short*       h1wr = h1p[(t + 1) & 1];
        const unsigned short* h2rd = h2p[t & 1];
        unsigned short*       h2wr = h2p[(t + 1) & 1];

        // ---- phase 1a: issue L0 A-loads (h1(t-1), readiness = flagA(t-1),
        // confirmed last step). They fly during phase 2's poll in AR. ----
        if (t != 255) {
            #pragma unroll
            for (int ks = 0; ks < 8; ++ks)
                lstm9_ldA(rP[ks], h1rd + (size_t)rowA * NH + ks * 32 + quad * 8);
            #pragma unroll
            for (int ks = 0; ks < 8; ++ks)
                lstm9_ldA(rQ[ks], h1rd + (size_t)rowA * NH + (8 + ks) * 32 + quad * 8);
        }

        // ---- phase 2: x (TF) or y-reduce (AR) ----
        float xv[4] = {0.f, 0.f, 0.f, 0.f};
        if (t < 128) {
            #pragma unroll
            for (int r = 0; r < 4; ++r)
                xv[r] = xin[(size_t)(mb + r) * NT + t];
        } else {
            lstm9_waitgrp(flagB + ((t - 1) * 8 + g) * 32);
            const float* pslot = parts + (size_t)((t - 1) & 1) * NB * 32;
            {
                const int row = tid >> 2, q = tid & 3;
                u32x4 v0, v1;
                lstm9_ldP(v0, pslot + (size_t)(m0 + row) * 32 + q * 8);
                lstm9_ldP(v1, pslot + (size_t)(m0 + row) * 32 + q * 8 + 4);
                LSTM9_WAIT2(v0, v1);
                const float* f0 = (const float*)&v0;
                const float* f1 = (const float*)&v1;
                redsh[row][q] = f0[0] + f0[1] + f0[2] + f0[3]
                              + f1[0] + f1[1] + f1[2] + f1[3];
            }
            __syncthreads();
            if (tid < 64) {
                const float y = bl_ + redsh[tid][0] + redsh[tid][1]
                                    + redsh[tid][2] + redsh[tid][3];
                ysh[tid] = y;
                if (jt == 0)
                    outf[(size_t)(m0 + tid) * NT + (t - 128)] = y;
            }
            __syncthreads();
            if (t == 255) break;   // last y published; done
            #pragma unroll
            for (int r = 0; r < 4; ++r)
                xv[r] = ysh[wv * 16 + quad * 4 + r];
        }

        // ---- phase 1b: L0 MFMAs: gates = h1(t-1) @ w_hh0^T (B from LDS) ----
        f32x4 a0 = {0.f, 0.f, 0.f, 0.f};
        f32x4 a1 = a0, a2 = a0, a3 = a0;
        LSTM9_W8(8, rP[0], rP[1], rP[2], rP[3], rP[4], rP[5], rP[6], rP[7]);
        #pragma unroll
        for (int ks = 0; ks < 8; ++ks) {
            const bf16x8 af = *(const bf16x8*)&rP[ks];
            a0 = __builtin_amdgcn_mfma_f32_16x16x32_bf16(af, BFR0(0, ks), a0, 0, 0, 0);
            a1 = __builtin_amdgcn_mfma_f32_16x16x32_bf16(af, BFR0(1, ks), a1, 0, 0, 0);
            a2 = __builtin_amdgcn_mfma_f32_16x16x32_bf16(af, BFR0(2, ks), a2, 0, 0, 0);
            a3 = __builtin_amdgcn_mfma_f32_16x16x32_bf16(af, BFR0(3, ks), a3, 0, 0, 0);
        }
        LSTM9_W8(0, rQ[0], rQ[1], rQ[2], rQ[3], rQ[4], rQ[5], rQ[6], rQ[7]);
        #pragma unroll
        for (int ks = 0; ks < 8; ++ks) {
            const bf16x8 af = *(const bf16x8*)&rQ[ks];
            a0 = __builtin_amdgcn_mfma_f32_16x16x32_bf16(af, BFR0(0, 8 + ks), a0, 0, 0, 0);
            a1 = __builtin_amdgcn_mfma_f32_16x16x32_bf16(af, BFR0(1, 8 + ks), a1, 0, 0, 0);
            a2 = __builtin_amdgcn_mfma_f32_16x16x32_bf16(af, BFR0(2, 8 + ks), a2, 0, 0, 0);
            a3 = __builtin_amdgcn_mfma_f32_16x16x32_bf16(af, BFR0(3, 8 + ks), a3, 0, 0, 0);
        }

        // ---- phase 3: L0 epilogue, h1(t) stores, flagA ----
        #pragma unroll
        for (int r = 0; r < 4; ++r) {
            const float gi = a0[r] + fmaf(xv[r], wxi, b0i);
            const float gf = a1[r] + fmaf(xv[r], wxf, b0f);
            const float gg = a2[r] + fmaf(xv[r], wxg, b0g);
            const float go = a3[r] + fmaf(xv[r], wxo, b0o);
            float cv = c1r[r];
            cv = lstm9_sig(gf) * cv + lstm9_sig(gi) * tanhf(gg);
            c1r[r] = cv;
            lstm9_stH(h1wr + (size_t)(mb + r) * NH + jv,
                      lstm9_f2b(lstm9_sig(go) * tanhf(cv)));
        }
        lstm9_drain();
        __syncthreads();
        if (tid == 0) lstm9_stI(flagA + (t * 8 + g) * 32 + jt, 1);

        // ---- phase 4: ONE merged poll (TF); AR already did flagB in phase 2
        if (t < 128) {
            const int* bA = flagA + (t * 8 + g) * 32;
            const int* bB = (t >= 1) ? (flagB + ((t - 1) * 8 + g) * 32) : bA;
            lstm9_waitgrp2(bA, bB);
        } else {
            lstm9_waitgrp(flagA + (t * 8 + g) * 32);
        }

        // ---- phase 5: L1 MFMAs, pipelined.
        // h2-part B from registers (whr), h1-part B from LDS (Bsh1). ----
        a0 = {0.f, 0.f, 0.f, 0.f}; a1 = a0; a2 = a0; a3 = a0;
        #pragma unroll
        for (int ks = 0; ks < 8; ++ks)
            lstm9_ldA(rP[ks], h2rd + (size_t)rowA * NH + ks * 32 + quad * 8);
        #pragma unroll
        for (int ks = 0; ks < 8; ++ks)
            lstm9_ldA(rQ[ks], h2rd + (size_t)rowA * NH + (8 + ks) * 32 + quad * 8);
        LSTM9_W8(8, rP[0], rP[1], rP[2], rP[3], rP[4], rP[5], rP[6], rP[7]);
        #pragma unroll
        for (int ks = 0; ks < 8; ++ks) {
            const bf16x8 af = *(const bf16x8*)&rP[ks];
            a0 = __builtin_amdgcn_mfma_f32_16x16x32_bf16(af, WHR(0, ks), a0, 0, 0, 0);
            a1 = __builtin_amdgcn_mfma_f32_16x16x32_bf16(af, WHR(1, ks), a1, 0, 0, 0);
            a2 = __builtin_amdgcn_mfma_f32_16x16x32_bf16(af, WHR(2, ks), a2, 0, 0, 0);
            a3 = __builtin_amdgcn_mfma_f32_16x16x32_bf16(af, WHR(3, ks), a3, 0, 0, 0);
        }
        #pragma unroll
        for (int ks = 0; ks < 8; ++ks)
            lstm9_ldA(rP[ks], h1wr + (size_t)rowA * NH + ks * 32 + quad * 8);
        LSTM9_W8(8, rQ[0], rQ[1], rQ[2], rQ[3], rQ[4], rQ[5], rQ[6], rQ[7]);
        #pragma unroll
        for (int ks = 0; ks < 8; ++ks) {
            const bf16x8 af = *(const bf16x8*)&rQ[ks];
            a0 = __builtin_amdgcn_mfma_f32_16x16x32_bf16(af, WHR(0, 8 + ks), a0, 0, 0, 0);
            a1 = __builtin_amdgcn_mfma_f32_16x16x32_bf16(af, WHR(1, 8 + ks), a1, 0, 0, 0);
            a2 = __builtin_amdgcn_mfma_f32_16x16x32_bf16(af, WHR(2, 8 + ks), a2, 0, 0, 0);
            a3 = __builtin_amdgcn_mfma_f32_16x16x32_bf16(af, WHR(3, 8 + ks), a3, 0, 0, 0);
        }
        #pragma unroll
        for (int ks = 0; ks < 8; ++ks)
            lstm9_ldA(rQ[ks], h1wr + (size_t)rowA * NH + (8 + ks) * 32 + quad * 8);
        LSTM9_W8(8, rP[0], rP[1], rP[2], rP[3], rP[4], rP[5], rP[6], rP[7]);
        #pragma unroll
        for (int ks = 0; ks < 8; ++ks) {
            const bf16x8 af = *(const bf16x8*)&rP[ks];
            a0 = __builtin_amdgcn_mfma_f32_16x16x32_bf16(af, BFR1(0, ks), a0, 0, 0, 0);
            a1 = __builtin_amdgcn_mfma_f32_16x16x32_bf16(af, BFR1(1, ks), a1, 0, 0, 0);
            a2 = __builtin_amdgcn_mfma_f32_16x16x32_bf16(af, BFR1(2, ks), a2, 0, 0, 0);
            a3 = __builtin_amdgcn_mfma_f32_16x16x32_bf16(af, BFR1(3, ks), a3, 0, 0, 0);
        }
        LSTM9_W8(0, rQ[0], rQ[1], rQ[2], rQ[3], rQ[4], rQ[5], rQ[6], rQ[7]);
        #pragma unroll
        for (int ks = 0; ks < 8; ++ks) {
            const bf16x8 af = *(const bf16x8*)&rQ[ks];
            a0 = __builtin_amdgcn_mfma_f32_16x16x32_bf16(af, BFR1(0, 8 + ks), a0, 0, 0, 0);
            a1 = __builtin_amdgcn_mfma_f32_16x16x32_bf16(af, BFR1(1, 8 + ks), a1, 0, 0, 0);
            a2 = __builtin_amdgcn_mfma_f32_16x16x32_bf16(af, BFR1(2, 8 + ks), a2, 0, 0, 0);
            a3 = __builtin_amdgcn_mfma_f32_16x16x32_bf16(af, BFR1(3, 8 + ks), a3, 0, 0, 0);
        }

        // ---- phase 6: L1 epilogue, h2(t) stores, parts, flagB ----
        float hv[4], cva[4];
        #pragma unroll
        for (int r = 0; r < 4; ++r) {
            const float gi = a0[r] + b1i;
            const float gf = a1[r] + b1f;
            const float gg = a2[r] + b1g;
            const float go = a3[r] + b1o;
            float cv = c2r[r];
            cv = lstm9_sig(gf) * cv + lstm9_sig(gi) * tanhf(gg);
            c2r[r] = cv;
            cva[r] = cv;
            hv[r] = lstm9_sig(go) * tanhf(cv);
            lstm9_stH(h2wr + (size_t)(mb + r) * NH + jv, lstm9_f2b(hv[r]));
        }
        if (t >= 127) {
            // partial dot for y(t-127): t==127 uses CELL state (ref quirk)
            #pragma unroll
            for (int r = 0; r < 4; ++r)
                redsh[wv * 16 + quad * 4 + r][ln15] =
                    (t == 127 ? cva[r] : hv[r]) * wl_;
            __syncthreads();
            if (tid < 64) {
                float s = 0.0f;
                #pragma unroll
                for (int j = 0; j < 16; ++j) s += redsh[tid][j];
                lstm9_stF(parts + (size_t)(t & 1) * NB * 32
                                + (size_t)(m0 + tid) * 32 + jt, s);
            }
        }
        lstm9_drain();
        __syncthreads();
        if (tid == 0) lstm9_stI(flagB + (t * 8 + g) * 32 + jt, 1);
    }
}

extern "C" void kernel_launch(void* const* d_in, const int* in_sizes, int n_in,
                              void* d_out, int out_size, void* d_ws, size_t ws_size,
                              hipStream_t stream)
{
    int base = 3;
    if (!(n_in > 3 && in_sizes[3] == 4 * NH)) {
        for (int i = 1; i + 9 < n_in; ++i)
            if (in_sizes[i] == 4 * NH) { base = i; break; }
    }
    const float* xin  = (const float*)d_in[0];
    const float* wih0 = (const float*)d_in[base + 0];
    const float* whh0 = (const float*)d_in[base + 1];
    const float* bih0 = (const float*)d_in[base + 2];
    const float* bhh0 = (const float*)d_in[base + 3];
    const float* wih1 = (const float*)d_in[base + 4];
    const float* whh1 = (const float*)d_in[base + 5];
    const float* bih1 = (const float*)d_in[base + 6];
    const float* bhh1 = (const float*)d_in[base + 7];
    const float* wlin = (const float*)d_in[base + 8];
    const float* blin = (const float*)d_in[base + 9];
    float* outf = (float*)d_out;

    // ws layout (~9 MB): bf16 weights | bf16 h ping-pong | fp32 bias |
    // y-partials | flags.
    const size_t NW = (size_t)4 * NH * NH;
    const size_t S  = (size_t)NB * NH;
    unsigned short* wb0  = (unsigned short*)d_ws;
    unsigned short* wb1i = wb0 + NW;
    unsigned short* wb1h = wb1i + NW;
    unsigned short* h1b0 = wb1h + NW;
    unsigned short* h1b1 = h1b0 + S;
    unsigned short* h2b0 = h1b1 + S;
    unsigned short* h2b1 = h2b0 + S;
    float* bsum0 = (float*)(h2b1 + S);
    float* bsum1 = bsum0 + 4 * NH;
    float* parts = bsum1 + 4 * NH;               // 2 slots x 512 m x 32 j
    int*   flags = (int*)(parts + 2 * NB * 32);  // flagA | flagB

    lstm9_mark<<<(NB * NT + 255) / 256, 256, 0, stream>>>(outf);
    lstm9_prep<<<1024, 256, 0, stream>>>(whh0, wih1, whh1, bih0, bhh0, bih1, bhh1,
                                         wb0, wb1i, wb1h, bsum0, bsum1,
                                         h1b0, flags);
    lstm9_persist<<<256, 256, 0, stream>>>(xin, outf, wb0, wb1i, wb1h,
                                           bsum0, bsum1, wih0, wlin, blin,
                                           h1b0, h1b1, h2b0, h2b1,
                                           parts, flags);
}

// Round 5
// 3409.118 us; speedup vs baseline: 1.9198x; 1.0645x over previous
//
#include <hip/hip_runtime.h>
#include <math.h>
#include <stdint.h>

// ReLSTM_18940805775611 — B=512, T=128, H=512, 2-layer LSTM, 128 TF + 127 AR.
// R23 (3629us, best): persistent, wb0/wb1i LDS-resident fragments, wb1h in
// 256 VGPRs, c in regs, pipelined A-loads. Counters: 14.2us/step, MfmaUtil 9%,
// FETCH 1.06GB => sc0sc1 traffic is HBM/MALL-class latency; step = ~8 serial
// round trips, compute only ~3000cy. R24 cuts round trips:
//  (1) L1's h1wr fragments == next step's L0 A-fragments (same data, rows,
//      layout). Persist rA1/rA2 across the loop -> L0 A-load + its bare RT
//      GONE (TF phase-1a eliminated).
//  (2) Phase 5 issues ALL 32 loads (h2rd 16 + h1wr 16) after the merged poll;
//      counted-vmcnt ladder W(24)/W(16)/W(8)/W(0) with 32 MFMAs per rung ->
//      ONE bare RT for the whole of L1 (was 2-3).
//  (3) AR: parts loads issue before L0's 64 register-A MFMAs -> parts RT
//      hidden under compute (y only enters at the epilogue).
//  (4) Poll backoff (sleep 1 -> 8 after 4 tries) to tame the 44ms outliers.
// Flag/ping-pong/WAR protocol unchanged from R21/R23 (all cases re-derived
// with the new load placement: flagA(t) covers h1wr reads, flagB(t-1) covers
// h2rd reads; register reuse adds no memory hazard).
// VGPR budget: whr 256 + in-flight frags 128 + acc/state ~60 => ~450 of 512.

namespace {
constexpr int NH  = 512;    // hidden
constexpr int NT  = 128;    // seq len
constexpr int NB  = 512;    // batch
}

typedef __attribute__((ext_vector_type(8))) short bf16x8;
typedef __attribute__((ext_vector_type(4))) float f32x4;
typedef __attribute__((ext_vector_type(4))) unsigned int u32x4;

// Present in case the harness resolves this symbol.
__global__ void ReLSTM_18940805775611_kernel() {}

__device__ __forceinline__ unsigned short lstm9_f2b(float f) {
    union { float f; uint32_t i; } v; v.f = f;
    const uint32_t r = v.i + 0x7FFFu + ((v.i >> 16) & 1u);   // RNE
    return (unsigned short)(r >> 16);
}
__device__ __forceinline__ float lstm9_sig(float x) {
    return 1.0f / (1.0f + expf(-x));
}

// ---- sentinel: truncation diagnostic ----
__global__ void lstm9_mark(float* out) {
    const int i = blockIdx.x * blockDim.x + threadIdx.x;
    if (i < NB * NT) out[i] = 2.03125f;
}

// ---- one-time prep: weights fp32->bf16 (RNE), summed biases, zero states,
// zero flags ----
__global__ void lstm9_prep(
    const float* whh0, const float* wih1, const float* whh1,
    const float* bih0, const float* bhh0, const float* bih1, const float* bhh1,
    unsigned short* wb0, unsigned short* wb1i, unsigned short* wb1h,
    float* bsum0, float* bsum1,
    unsigned short* hz, int* flags)
{
    const size_t stride = (size_t)gridDim.x * blockDim.x;
    const size_t i0 = (size_t)blockIdx.x * blockDim.x + threadIdx.x;
    const size_t NW = (size_t)4 * NH * NH;
    for (size_t i = i0; i < NW; i += stride) {
        wb0 [i] = lstm9_f2b(whh0[i]);
        wb1i[i] = lstm9_f2b(wih1[i]);
        wb1h[i] = lstm9_f2b(whh1[i]);
    }
    for (size_t i = i0; i < (size_t)4 * NH; i += stride) {
        bsum0[i] = bih0[i] + bhh0[i];
        bsum1[i] = bih1[i] + bhh1[i];
    }
    for (size_t i = i0; i < (size_t)4 * NB * NH; i += stride) hz[i] = 0;
    for (size_t i = i0; i < (size_t)2 * 256 * 8 * 32; i += stride) flags[i] = 0;
}

// ---- asm memory helpers (sc0 sc1 = bypass L1+L2, coherent past L2) ----
__device__ __forceinline__ void lstm9_ldA(u32x4& d, const unsigned short* p) {
    asm volatile("global_load_dwordx4 %0, %1, off sc0 sc1"
                 : "=v"(d) : "v"(p) : "memory");
}
__device__ __forceinline__ void lstm9_ldP(u32x4& d, const float* p) {
    asm volatile("global_load_dwordx4 %0, %1, off sc0 sc1"
                 : "=v"(d) : "v"(p) : "memory");
}
#define LSTM9_W8(N, a,b,c,d,e,f,g,h) \
    asm volatile("s_waitcnt vmcnt(" #N ")" \
        : "+v"(a),"+v"(b),"+v"(c),"+v"(d),"+v"(e),"+v"(f),"+v"(g),"+v"(h) :: "memory")
#define LSTM9_WAIT2(a,b) \
    asm volatile("s_waitcnt vmcnt(0)" : "+v"(a),"+v"(b) :: "memory")
__device__ __forceinline__ void lstm9_stH(unsigned short* p, unsigned short v) {
    unsigned int x = v;
    asm volatile("global_store_short %0, %1, off sc0 sc1" :: "v"(p), "v"(x) : "memory");
}
__device__ __forceinline__ void lstm9_stF(float* p, float v) {
    asm volatile("global_store_dword %0, %1, off sc0 sc1" :: "v"(p), "v"(v) : "memory");
}
__device__ __forceinline__ void lstm9_stI(int* p, int v) {
    asm volatile("global_store_dword %0, %1, off sc0 sc1" :: "v"(p), "v"(v) : "memory");
}
__device__ __forceinline__ void lstm9_drain() {
    asm volatile("s_waitcnt vmcnt(0)" ::: "memory");
}

// ---- group barriers: wait until all 32 flag slots of a group are set ----
__device__ __forceinline__ void lstm9_waitgrp(const int* base) {
    if (threadIdx.x < 64) {
        const int sl = (int)threadIdx.x & 31;
        int it = 0;
        for (;;) {
            int f;
            asm volatile("global_load_dword %0, %1, off sc0 sc1\n\t"
                         "s_waitcnt vmcnt(0)"
                         : "=v"(f) : "v"(base + sl) : "memory");
            if (__all(f != 0)) break;
            if (it < 4) __builtin_amdgcn_s_sleep(1);
            else        __builtin_amdgcn_s_sleep(8);
            ++it;
        }
    }
    __syncthreads();
}
// merged: lanes 0-31 poll baseA, lanes 32-63 poll baseB (one round trip)
__device__ __forceinline__ void lstm9_waitgrp2(const int* baseA, const int* baseB) {
    if (threadIdx.x < 64) {
        const int sl = (int)threadIdx.x & 31;
        const int* p = ((threadIdx.x < 32) ? baseA : baseB) + sl;
        int it = 0;
        for (;;) {
            int f;
            asm volatile("global_load_dword %0, %1, off sc0 sc1\n\t"
                         "s_waitcnt vmcnt(0)"
                         : "=v"(f) : "v"(p) : "memory");
            if (__all(f != 0)) break;
            if (it < 4) __builtin_amdgcn_s_sleep(1);
            else        __builtin_amdgcn_s_sleep(8);
            ++it;
        }
    }
    __syncthreads();
}

#define BFR0(gt, kk) (*(const bf16x8*)&Bsh0[gt][kk][lane][0])
#define BFR1(gt, kk) (*(const bf16x8*)&Bsh1[gt][kk][lane][0])
#define WHR(gt, kk)  (*(const bf16x8*)&whr[(gt) * 16 + (kk)])

// L0 MFMAs: A = persisted rA1/rA2 (h1(t-1) fragments), B = Bsh0 (LDS).
#define LSTM9_L0_MFMAS()                                                          \
    do {                                                                          \
        _Pragma("unroll")                                                         \
        for (int ks = 0; ks < 8; ++ks) {                                          \
            const bf16x8 af = *(const bf16x8*)&rA1[ks];                           \
            a0 = __builtin_amdgcn_mfma_f32_16x16x32_bf16(af, BFR0(0, ks), a0, 0, 0, 0); \
            a1 = __builtin_amdgcn_mfma_f32_16x16x32_bf16(af, BFR0(1, ks), a1, 0, 0, 0); \
            a2 = __builtin_amdgcn_mfma_f32_16x16x32_bf16(af, BFR0(2, ks), a2, 0, 0, 0); \
            a3 = __builtin_amdgcn_mfma_f32_16x16x32_bf16(af, BFR0(3, ks), a3, 0, 0, 0); \
        }                                                                         \
        _Pragma("unroll")                                                         \
        for (int ks = 0; ks < 8; ++ks) {                                          \
            const bf16x8 af = *(const bf16x8*)&rA2[ks];                           \
            a0 = __builtin_amdgcn_mfma_f32_16x16x32_bf16(af, BFR0(0, 8 + ks), a0, 0, 0, 0); \
            a1 = __builtin_amdgcn_mfma_f32_16x16x32_bf16(af, BFR0(1, 8 + ks), a1, 0, 0, 0); \
            a2 = __builtin_amdgcn_mfma_f32_16x16x32_bf16(af, BFR0(2, 8 + ks), a2, 0, 0, 0); \
            a3 = __builtin_amdgcn_mfma_f32_16x16x32_bf16(af, BFR0(3, 8 + ks), a3, 0, 0, 0); \
        }                                                                         \
    } while (0)

// ---- the persistent kernel: all 255 steps (128 TF + 127 AR) ----
__global__ __launch_bounds__(256, 1) void lstm9_persist(
    const float* __restrict__ xin, float* __restrict__ outf,
    const unsigned short* __restrict__ wb0,
    const unsigned short* __restrict__ wb1i,
    const unsigned short* __restrict__ wb1h,
    const float* __restrict__ bsum0, const float* __restrict__ bsum1,
    const float* __restrict__ wih0f, const float* __restrict__ wlinf,
    const float* __restrict__ blinf,
    unsigned short* h1a, unsigned short* h1b,
    unsigned short* h2a, unsigned short* h2b,
    float* parts, int* flags)
{
    __shared__ unsigned short Bsh0[4][16][64][8];   // w_hh0 fragments, 64KB
    __shared__ unsigned short Bsh1[4][16][64][8];   // w_ih1 fragments, 64KB
    __shared__ float redsh[64][17];
    __shared__ float ysh[64];

    const int tid  = threadIdx.x;
    const int lane = tid & 63;
    const int wv   = tid >> 6;        // 0..3 -> m-subtile (16 rows each)
    const int quad = lane >> 4;
    const int ln15 = lane & 15;
    const int bid  = blockIdx.x;
    const int jt = (bid & 7) * 4 + ((bid >> 3) & 3);  // j-tile 0..31 (XCD spread)
    const int g  = bid >> 5;                          // m-group 0..7
    const int j0 = jt * 16;
    const int m0 = g * 64;
    const int rowA = m0 + wv * 16 + ln15;             // A-fragment row
    const int mb   = m0 + wv * 16 + quad * 4;         // epilogue row base
    const int jv   = j0 + ln15;

    // ---- one-time: wb0/wb1i into LDS in fragment order ----
    for (int idx = tid; idx < 4 * 16 * 64; idx += 256) {
        const int gt = idx >> 10;
        const int ks = (idx >> 6) & 15;
        const int l  = idx & 63;
        const int row = l & 15, q = l >> 4;
        const size_t go = ((size_t)(gt * NH + j0 + row)) * NH + ks * 32 + q * 8;
        *(u32x4*)&Bsh0[gt][ks][l][0] = *(const u32x4*)(wb0  + go);
        *(u32x4*)&Bsh1[gt][ks][l][0] = *(const u32x4*)(wb1i + go);
    }
    // ---- one-time: wb1h fragments into 256 VGPRs/lane ----
    u32x4 whr[64];
    #pragma unroll
    for (int gt = 0; gt < 4; ++gt) {
        #pragma unroll
        for (int ks = 0; ks < 16; ++ks)
            whr[gt * 16 + ks] = *(const u32x4*)(
                wb1h + ((size_t)(gt * NH + j0 + ln15)) * NH + ks * 32 + quad * 8);
    }
    __syncthreads();

    // step-invariant scalars
    const float b0i = bsum0[jv],          b0f = bsum0[NH + jv];
    const float b0g = bsum0[2 * NH + jv], b0o = bsum0[3 * NH + jv];
    const float wxi = wih0f[jv],          wxf = wih0f[NH + jv];
    const float wxg = wih0f[2 * NH + jv], wxo = wih0f[3 * NH + jv];
    const float b1i = bsum1[jv],          b1f = bsum1[NH + jv];
    const float b1g = bsum1[2 * NH + jv], b1o = bsum1[3 * NH + jv];
    const float wl_ = wlinf[jv];
    const float bl_ = blinf[0];

    float c1r[4] = {0.f, 0.f, 0.f, 0.f};
    float c2r[4] = {0.f, 0.f, 0.f, 0.f};

    unsigned short* h1p[2] = { h1a, h1b };
    unsigned short* h2p[2] = { h2a, h2b };
    int* flagA = flags;
    int* flagB = flags + 256 * 8 * 32;

    // persisted A-fragments: h1(t-1) for L0. h1(-1) = 0.
    u32x4 rA1[8], rA2[8];
    #pragma unroll
    for (int ks = 0; ks < 8; ++ks) {
        rA1[ks] = (u32x4){0u, 0u, 0u, 0u};
        rA2[ks] = (u32x4){0u, 0u, 0u, 0u};
    }
    u32x4 rH2a[8], rH2b[8];

    for (int t = 0; t < 256; ++t) {
        unsigned short*       h1wr = h1p[(t + 1) & 1];
        const unsigned short* h2rd = h2p[t & 1];
        unsigned short*       h2wr = h2p[(t + 1) & 1];

        // ---- phase 1: x (TF) or y-reduce (AR); L0 MFMAs overlap parts RT ----
        float xv[4] = {0.f, 0.f, 0.f, 0.f};
        f32x4 a0 = {0.f, 0.f, 0.f, 0.f};
        f32x4 a1 = a0, a2 = a0, a3 = a0;
        if (t < 128) {
            #pragma unroll
            for (int r = 0; r < 4; ++r)
                xv[r] = xin[(size_t)(mb + r) * NT + t];
            LSTM9_L0_MFMAS();
        } else {
            lstm9_waitgrp(flagB + ((t - 1) * 8 + g) * 32);
            const float* pslot = parts + (size_t)((t - 1) & 1) * NB * 32;
            const int row = tid >> 2, q = tid & 3;
            u32x4 v0, v1;
            lstm9_ldP(v0, pslot + (size_t)(m0 + row) * 32 + q * 8);
            lstm9_ldP(v1, pslot + (size_t)(m0 + row) * 32 + q * 8 + 4);
            if (t < 255) LSTM9_L0_MFMAS();      // hide parts RT under compute
            LSTM9_WAIT2(v0, v1);
            const float* f0 = (const float*)&v0;
            const float* f1 = (const float*)&v1;
            redsh[row][q] = f0[0] + f0[1] + f0[2] + f0[3]
                          + f1[0] + f1[1] + f1[2] + f1[3];
            __syncthreads();
            if (tid < 64) {
                const float y = bl_ + redsh[tid][0] + redsh[tid][1]
                                    + redsh[tid][2] + redsh[tid][3];
                ysh[tid] = y;
                if (jt == 0)
                    outf[(size_t)(m0 + tid) * NT + (t - 128)] = y;
            }
            __syncthreads();
            if (t == 255) break;   // last y published; done
            #pragma unroll
            for (int r = 0; r < 4; ++r)
                xv[r] = ysh[wv * 16 + quad * 4 + r];
        }

        // ---- phase 2: L0 epilogue, h1(t) stores, flagA ----
        #pragma unroll
        for (int r = 0; r < 4; ++r) {
            const float gi = a0[r] + fmaf(xv[r], wxi, b0i);
            const float gf = a1[r] + fmaf(xv[r], wxf, b0f);
            const float gg = a2[r] + fmaf(xv[r], wxg, b0g);
            const float go = a3[r] + fmaf(xv[r], wxo, b0o);
            float cv = c1r[r];
            cv = lstm9_sig(gf) * cv + lstm9_sig(gi) * tanhf(gg);
            c1r[r] = cv;
            lstm9_stH(h1wr + (size_t)(mb + r) * NH + jv,
                      lstm9_f2b(lstm9_sig(go) * tanhf(cv)));
        }
        lstm9_drain();
        __syncthreads();
        if (tid == 0) lstm9_stI(flagA + (t * 8 + g) * 32 + jt, 1);

        // ---- phase 3: merged poll: flagA(t) (+ flagB(t-1) in TF) ----
        if (t < 128) {
            const int* bA = flagA + (t * 8 + g) * 32;
            const int* bB = (t >= 1) ? (flagB + ((t - 1) * 8 + g) * 32) : bA;
            lstm9_waitgrp2(bA, bB);
        } else {
            lstm9_waitgrp(flagA + (t * 8 + g) * 32);
        }

        // ---- phase 4: L1 — issue ALL 32 A-loads, counted-vmcnt ladder.
        // h2-part B from registers (whr); h1-part B from LDS (Bsh1).
        // rA1/rA2 (h1(t) fragments) persist into next step's L0. ----
        a0 = {0.f, 0.f, 0.f, 0.f}; a1 = a0; a2 = a0; a3 = a0;
        #pragma unroll
        for (int ks = 0; ks < 8; ++ks)
            lstm9_ldA(rH2a[ks], h2rd + (size_t)rowA * NH + ks * 32 + quad * 8);
        #pragma unroll
        for (int ks = 0; ks < 8; ++ks)
            lstm9_ldA(rH2b[ks], h2rd + (size_t)rowA * NH + (8 + ks) * 32 + quad * 8);
        #pragma unroll
        for (int ks = 0; ks < 8; ++ks)
            lstm9_ldA(rA1[ks], h1wr + (size_t)rowA * NH + ks * 32 + quad * 8);
        #pragma unroll
        for (int ks = 0; ks < 8; ++ks)
            lstm9_ldA(rA2[ks], h1wr + (size_t)rowA * NH + (8 + ks) * 32 + quad * 8);

        LSTM9_W8(24, rH2a[0], rH2a[1], rH2a[2], rH2a[3],
                     rH2a[4], rH2a[5], rH2a[6], rH2a[7]);
        #pragma unroll
        for (int ks = 0; ks < 8; ++ks) {
            const bf16x8 af = *(const bf16x8*)&rH2a[ks];
            a0 = __builtin_amdgcn_mfma_f32_16x16x32_bf16(af, WHR(0, ks), a0, 0, 0, 0);
            a1 = __builtin_amdgcn_mfma_f32_16x16x32_bf16(af, WHR(1, ks), a1, 0, 0, 0);
            a2 = __builtin_amdgcn_mfma_f32_16x16x32_bf16(af, WHR(2, ks), a2, 0, 0, 0);
            a3 = __builtin_amdgcn_mfma_f32_16x16x32_bf16(af, WHR(3, ks), a3, 0, 0, 0);
        }
        LSTM9_W8(16, rH2b[0], rH2b[1], rH2b[2], rH2b[3],
                     rH2b[4], rH2b[5], rH2b[6], rH2b[7]);
        #pragma unroll
        for (int ks = 0; ks < 8; ++ks) {
            const bf16x8 af = *(const bf16x8*)&rH2b[ks];
            a0 = __builtin_amdgcn_mfma_f32_16x16x32_bf16(af, WHR(0, 8 + ks), a0, 0, 0, 0);
            a1 = __builtin_amdgcn_mfma_f32_16x16x32_bf16(af, WHR(1, 8 + ks), a1, 0, 0, 0);
            a2 = __builtin_amdgcn_mfma_f32_16x16x32_bf16(af, WHR(2, 8 + ks), a2, 0, 0, 0);
            a3 = __builtin_amdgcn_mfma_f32_16x16x32_bf16(af, WHR(3, 8 + ks), a3, 0, 0, 0);
        }
        LSTM9_W8(8, rA1[0], rA1[1], rA1[2], rA1[3],
                    rA1[4], rA1[5], rA1[6], rA1[7]);
        #pragma unroll
        for (int ks = 0; ks < 8; ++ks) {
            const bf16x8 af = *(const bf16x8*)&rA1[ks];
            a0 = __builtin_amdgcn_mfma_f32_16x16x32_bf16(af, BFR1(0, ks), a0, 0, 0, 0);
            a1 = __builtin_amdgcn_mfma_f32_16x16x32_bf16(af, BFR1(1, ks), a1, 0, 0, 0);
            a2 = __builtin_amdgcn_mfma_f32_16x16x32_bf16(af, BFR1(2, ks), a2, 0, 0, 0);
            a3 = __builtin_amdgcn_mfma_f32_16x16x32_bf16(af, BFR1(3, ks), a3, 0, 0, 0);
        }
        LSTM9_W8(0, rA2[0], rA2[1], rA2[2], rA2[3],
                    rA2[4], rA2[5], rA2[6], rA2[7]);
        #pragma unroll
        for (int ks = 0; ks < 8; ++ks) {
            const bf16x8 af = *(const bf16x8*)&rA2[ks];
            a0 = __builtin_amdgcn_mfma_f32_16x16x32_bf16(af, BFR1(0, 8 + ks), a0, 0, 0, 0);
            a1 = __builtin_amdgcn_mfma_f32_16x16x32_bf16(af, BFR1(1, 8 + ks), a1, 0, 0, 0);
            a2 = __builtin_amdgcn_mfma_f32_16x16x32_bf16(af, BFR1(2, 8 + ks), a2, 0, 0, 0);
            a3 = __builtin_amdgcn_mfma_f32_16x16x32_bf16(af, BFR1(3, 8 + ks), a3, 0, 0, 0);
        }

        // ---- phase 5: L1 epilogue, h2(t) stores, parts, flagB ----
        float hv[4], cva[4];
        #pragma unroll
        for (int r = 0; r < 4; ++r) {
            const float gi = a0[r] + b1i;
            const float gf = a1[r] + b1f;
            const float gg = a2[r] + b1g;
            const float go = a3[r] + b1o;
            float cv = c2r[r];
            cv = lstm9_sig(gf) * cv + lstm9_sig(gi) * tanhf(gg);
            c2r[r] = cv;
            cva[r] = cv;
            hv[r] = lstm9_sig(go) * tanhf(cv);
            lstm9_stH(h2wr + (size_t)(mb + r) * NH + jv, lstm9_f2b(hv[r]));
        }
        if (t >= 127) {
            // partial dot for y(t-127): t==127 uses CELL state (ref quirk)
            #pragma unroll
            for (int r = 0; r < 4; ++r)
                redsh[wv * 16 + quad * 4 + r][ln15] =
                    (t == 127 ? cva[r] : hv[r]) * wl_;
            __syncthreads();
            if (tid < 64) {
                float s = 0.0f;
                #pragma unroll
                for (int j = 0; j < 16; ++j) s += redsh[tid][j];
                lstm9_stF(parts + (size_t)(t & 1) * NB * 32
                                + (size_t)(m0 + tid) * 32 + jt, s);
            }
        }
        lstm9_drain();
        __syncthreads();
        if (tid == 0) lstm9_stI(flagB + (t * 8 + g) * 32 + jt, 1);
    }
}

extern "C" void kernel_launch(void* const* d_in, const int* in_sizes, int n_in,
                              void* d_out, int out_size, void* d_ws, size_t ws_size,
                              hipStream_t stream)
{
    int base = 3;
    if (!(n_in > 3 && in_sizes[3] == 4 * NH)) {
        for (int i = 1; i + 9 < n_in; ++i)
            if (in_sizes[i] == 4 * NH) { base = i; break; }
    }
    const float* xin  = (const float*)d_in[0];
    const float* wih0 = (const float*)d_in[base + 0];
    const float* whh0 = (const float*)d_in[base + 1];
    const float* bih0 = (const float*)d_in[base + 2];
    const float* bhh0 = (const float*)d_in[base + 3];
    const float* wih1 = (const float*)d_in[base + 4];
    const float* whh1 = (const float*)d_in[base + 5];
    const float* bih1 = (const float*)d_in[base + 6];
    const float* bhh1 = (const float*)d_in[base + 7];
    const float* wlin = (const float*)d_in[base + 8];
    const float* blin = (const float*)d_in[base + 9];
    float* outf = (float*)d_out;

    // ws layout (~9 MB): bf16 weights | bf16 h ping-pong | fp32 bias |
    // y-partials | flags.
    const size_t NW = (size_t)4 * NH * NH;
    const size_t S  = (size_t)NB * NH;
    unsigned short* wb0  = (unsigned short*)d_ws;
    unsigned short* wb1i = wb0 + NW;
    unsigned short* wb1h = wb1i + NW;
    unsigned short* h1b0 = wb1h + NW;
    unsigned short* h1b1 = h1b0 + S;
    unsigned short* h2b0 = h1b1 + S;
    unsigned short* h2b1 = h2b0 + S;
    float* bsum0 = (float*)(h2b1 + S);
    float* bsum1 = bsum0 + 4 * NH;
    float* parts = bsum1 + 4 * NH;               // 2 slots x 512 m x 32 j
    int*   flags = (int*)(parts + 2 * NB * 32);  // flagA | flagB

    lstm9_mark<<<(NB * NT + 255) / 256, 256, 0, stream>>>(outf);
    lstm9_prep<<<1024, 256, 0, stream>>>(whh0, wih1, whh1, bih0, bhh0, bih1, bhh1,
                                         wb0, wb1i, wb1h, bsum0, bsum1,
                                         h1b0, flags);
    lstm9_persist<<<256, 256, 0, stream>>>(xin, outf, wb0, wb1i, wb1h,
                                           bsum0, bsum1, wih0, wlin, blin,
                                           h1b0, h1b1, h2b0, h2b1,
                                           parts, flags);
}

// Round 6
// 3075.707 us; speedup vs baseline: 2.1280x; 1.1084x over previous
//
#include <hip/hip_runtime.h>
#include <math.h>
#include <stdint.h>

// ReLSTM_18940805775611 — B=512, T=128, H=512, 2-layer LSTM, 128 TF + 127 AR.
// R23 (3629us): persistent, weights LDS/VGPR-resident, c in regs.
// R24 (3409us): rA persistence + 32-load vmcnt ladder + parts-RT hiding.
// Counters (R24): 13.5us/step, MfmaUtil 9.8%, compute ~1.3us -> the step is
// dominated by TWO flag-barrier sequences (drain + flag flight + poll detect
// + 32-block skew ~4-5us each). R25 halves that:
//  ITER(t) = L1(t) + L0(t+1)  [layer-boundary fusion]
//  - after the flagA(t) poll a block has h1(t) fragments loaded for L1(t)'s
//    h1-part; L0(t+1) consumes the SAME registers (A=h1(t)) -> zero extra
//    loads, +64 MFMAs that run while h2 stores fly.
//  - TF: ONE poll (merged flagA(t)&flagB(t-1)), ONE drain (h2(t)+h1(t+1)),
//    flagB(t)+flagA(t+1) stored back-to-back. Barriers/step: 2 -> 1.
//  - AR: y(t+1-128) = wlin . h2(t) is a cross-j reduction -> keep the parts
//    mini-barrier, but L0's 64 MFMAs sit between flagB store and flagB poll
//    (hidden under flag skew).
//  - WAR: flagB(t) is set only after the vmcnt ladder drained h1(t)/h2(t-1)
//    loads, so the top-of-loop poll of flagA(t)&flagB(t-1) certifies all
//    readers of the buffers ITER(t) overwrites. Prologue computes h1(0)
//    directly (h1(-1)=0 -> pure epilogue).
// LDS ~133KB; 256 blocks = 256 CUs; 256 thr; weights: wb0/wb1i LDS, wb1h VGPR.

namespace {
constexpr int NH  = 512;    // hidden
constexpr int NT  = 128;    // seq len
constexpr int NB  = 512;    // batch
}

typedef __attribute__((ext_vector_type(8))) short bf16x8;
typedef __attribute__((ext_vector_type(4))) float f32x4;
typedef __attribute__((ext_vector_type(4))) unsigned int u32x4;

// Present in case the harness resolves this symbol.
__global__ void ReLSTM_18940805775611_kernel() {}

__device__ __forceinline__ unsigned short lstm9_f2b(float f) {
    union { float f; uint32_t i; } v; v.f = f;
    const uint32_t r = v.i + 0x7FFFu + ((v.i >> 16) & 1u);   // RNE
    return (unsigned short)(r >> 16);
}
__device__ __forceinline__ float lstm9_sig(float x) {
    return 1.0f / (1.0f + expf(-x));
}

// ---- sentinel: truncation diagnostic ----
__global__ void lstm9_mark(float* out) {
    const int i = blockIdx.x * blockDim.x + threadIdx.x;
    if (i < NB * NT) out[i] = 2.03125f;
}

// ---- one-time prep: weights fp32->bf16 (RNE), summed biases, zero states,
// zero flags ----
__global__ void lstm9_prep(
    const float* whh0, const float* wih1, const float* whh1,
    const float* bih0, const float* bhh0, const float* bih1, const float* bhh1,
    unsigned short* wb0, unsigned short* wb1i, unsigned short* wb1h,
    float* bsum0, float* bsum1,
    unsigned short* hz, int* flags)
{
    const size_t stride = (size_t)gridDim.x * blockDim.x;
    const size_t i0 = (size_t)blockIdx.x * blockDim.x + threadIdx.x;
    const size_t NW = (size_t)4 * NH * NH;
    for (size_t i = i0; i < NW; i += stride) {
        wb0 [i] = lstm9_f2b(whh0[i]);
        wb1i[i] = lstm9_f2b(wih1[i]);
        wb1h[i] = lstm9_f2b(whh1[i]);
    }
    for (size_t i = i0; i < (size_t)4 * NH; i += stride) {
        bsum0[i] = bih0[i] + bhh0[i];
        bsum1[i] = bih1[i] + bhh1[i];
    }
    for (size_t i = i0; i < (size_t)4 * NB * NH; i += stride) hz[i] = 0;
    for (size_t i = i0; i < (size_t)2 * 256 * 8 * 32; i += stride) flags[i] = 0;
}

// ---- asm memory helpers (sc0 sc1 = bypass L1+L2, coherent past L2) ----
__device__ __forceinline__ void lstm9_ldA(u32x4& d, const unsigned short* p) {
    asm volatile("global_load_dwordx4 %0, %1, off sc0 sc1"
                 : "=v"(d) : "v"(p) : "memory");
}
__device__ __forceinline__ void lstm9_ldP(u32x4& d, const float* p) {
    asm volatile("global_load_dwordx4 %0, %1, off sc0 sc1"
                 : "=v"(d) : "v"(p) : "memory");
}
#define LSTM9_W8(N, a,b,c,d,e,f,g,h) \
    asm volatile("s_waitcnt vmcnt(" #N ")" \
        : "+v"(a),"+v"(b),"+v"(c),"+v"(d),"+v"(e),"+v"(f),"+v"(g),"+v"(h) :: "memory")
#define LSTM9_WAIT2(a,b) \
    asm volatile("s_waitcnt vmcnt(0)" : "+v"(a),"+v"(b) :: "memory")
__device__ __forceinline__ void lstm9_stH(unsigned short* p, unsigned short v) {
    unsigned int x = v;
    asm volatile("global_store_short %0, %1, off sc0 sc1" :: "v"(p), "v"(x) : "memory");
}
__device__ __forceinline__ void lstm9_stF(float* p, float v) {
    asm volatile("global_store_dword %0, %1, off sc0 sc1" :: "v"(p), "v"(v) : "memory");
}
__device__ __forceinline__ void lstm9_stI(int* p, int v) {
    asm volatile("global_store_dword %0, %1, off sc0 sc1" :: "v"(p), "v"(v) : "memory");
}
__device__ __forceinline__ void lstm9_drain() {
    asm volatile("s_waitcnt vmcnt(0)" ::: "memory");
}

// ---- group barriers: wait until all 32 flag slots of a group are set ----
__device__ __forceinline__ void lstm9_waitgrp(const int* base) {
    if (threadIdx.x < 64) {
        const int sl = (int)threadIdx.x & 31;
        int it = 0;
        for (;;) {
            int f;
            asm volatile("global_load_dword %0, %1, off sc0 sc1\n\t"
                         "s_waitcnt vmcnt(0)"
                         : "=v"(f) : "v"(base + sl) : "memory");
            if (__all(f != 0)) break;
            if (it < 4) __builtin_amdgcn_s_sleep(1);
            else        __builtin_amdgcn_s_sleep(8);
            ++it;
        }
    }
    __syncthreads();
}
// merged: lanes 0-31 poll baseA, lanes 32-63 poll baseB (one round trip)
__device__ __forceinline__ void lstm9_waitgrp2(const int* baseA, const int* baseB) {
    if (threadIdx.x < 64) {
        const int sl = (int)threadIdx.x & 31;
        const int* p = ((threadIdx.x < 32) ? baseA : baseB) + sl;
        int it = 0;
        for (;;) {
            int f;
            asm volatile("global_load_dword %0, %1, off sc0 sc1\n\t"
                         "s_waitcnt vmcnt(0)"
                         : "=v"(f) : "v"(p) : "memory");
            if (__all(f != 0)) break;
            if (it < 4) __builtin_amdgcn_s_sleep(1);
            else        __builtin_amdgcn_s_sleep(8);
            ++it;
        }
    }
    __syncthreads();
}

#define BFR0(gt, kk) (*(const bf16x8*)&Bsh0[gt][kk][lane][0])
#define BFR1(gt, kk) (*(const bf16x8*)&Bsh1[gt][kk][lane][0])
#define WHR(gt, kk)  (*(const bf16x8*)&whr[(gt) * 16 + (kk)])

// L0 MFMAs for step t+1: A = rA1/rA2 (h1(t) fragments), B = Bsh0 (LDS).
#define LSTM9_L0_MFMAS()                                                          \
    do {                                                                          \
        _Pragma("unroll")                                                         \
        for (int ks = 0; ks < 8; ++ks) {                                          \
            const bf16x8 af = *(const bf16x8*)&rA1[ks];                           \
            b0 = __builtin_amdgcn_mfma_f32_16x16x32_bf16(af, BFR0(0, ks), b0, 0, 0, 0); \
            b1 = __builtin_amdgcn_mfma_f32_16x16x32_bf16(af, BFR0(1, ks), b1, 0, 0, 0); \
            b2 = __builtin_amdgcn_mfma_f32_16x16x32_bf16(af, BFR0(2, ks), b2, 0, 0, 0); \
            b3 = __builtin_amdgcn_mfma_f32_16x16x32_bf16(af, BFR0(3, ks), b3, 0, 0, 0); \
        }                                                                         \
        _Pragma("unroll")                                                         \
        for (int ks = 0; ks < 8; ++ks) {                                          \
            const bf16x8 af = *(const bf16x8*)&rA2[ks];                           \
            b0 = __builtin_amdgcn_mfma_f32_16x16x32_bf16(af, BFR0(0, 8 + ks), b0, 0, 0, 0); \
            b1 = __builtin_amdgcn_mfma_f32_16x16x32_bf16(af, BFR0(1, 8 + ks), b1, 0, 0, 0); \
            b2 = __builtin_amdgcn_mfma_f32_16x16x32_bf16(af, BFR0(2, 8 + ks), b2, 0, 0, 0); \
            b3 = __builtin_amdgcn_mfma_f32_16x16x32_bf16(af, BFR0(3, 8 + ks), b3, 0, 0, 0); \
        }                                                                         \
    } while (0)

// L0 epilogue: gates -> c1r, h1(t+1) stores (16 cols of this block)
#define LSTM9_L0_EPI(h1dst)                                                       \
    do {                                                                          \
        _Pragma("unroll")                                                         \
        for (int r = 0; r < 4; ++r) {                                             \
            const float gi = b0[r] + fmaf(xv[r], wxi, b0i);                       \
            const float gf = b1[r] + fmaf(xv[r], wxf, b0f);                       \
            const float gg = b2[r] + fmaf(xv[r], wxg, b0g);                       \
            const float go = b3[r] + fmaf(xv[r], wxo, b0o);                       \
            float cv = c1r[r];                                                    \
            cv = lstm9_sig(gf) * cv + lstm9_sig(gi) * tanhf(gg);                  \
            c1r[r] = cv;                                                          \
            lstm9_stH((h1dst) + (size_t)(mb + r) * NH + jv,                       \
                      lstm9_f2b(lstm9_sig(go) * tanhf(cv)));                      \
        }                                                                         \
    } while (0)

// ---- the persistent kernel: all 255 steps (128 TF + 127 AR) ----
__global__ __launch_bounds__(256, 1) void lstm9_persist(
    const float* __restrict__ xin, float* __restrict__ outf,
    const unsigned short* __restrict__ wb0,
    const unsigned short* __restrict__ wb1i,
    const unsigned short* __restrict__ wb1h,
    const float* __restrict__ bsum0, const float* __restrict__ bsum1,
    const float* __restrict__ wih0f, const float* __restrict__ wlinf,
    const float* __restrict__ blinf,
    unsigned short* h1a, unsigned short* h1b,
    unsigned short* h2a, unsigned short* h2b,
    float* parts, int* flags)
{
    __shared__ unsigned short Bsh0[4][16][64][8];   // w_hh0 fragments, 64KB
    __shared__ unsigned short Bsh1[4][16][64][8];   // w_ih1 fragments, 64KB
    __shared__ float redsh[64][17];
    __shared__ float ysh[64];

    const int tid  = threadIdx.x;
    const int lane = tid & 63;
    const int wv   = tid >> 6;        // 0..3 -> m-subtile (16 rows each)
    const int quad = lane >> 4;
    const int ln15 = lane & 15;
    const int bid  = blockIdx.x;
    const int jt = (bid & 7) * 4 + ((bid >> 3) & 3);  // j-tile 0..31 (XCD spread)
    const int g  = bid >> 5;                          // m-group 0..7
    const int j0 = jt * 16;
    const int m0 = g * 64;
    const int rowA = m0 + wv * 16 + ln15;             // A-fragment row
    const int mb   = m0 + wv * 16 + quad * 4;         // epilogue row base
    const int jv   = j0 + ln15;

    // ---- one-time: wb0/wb1i into LDS in fragment order ----
    for (int idx = tid; idx < 4 * 16 * 64; idx += 256) {
        const int gt = idx >> 10;
        const int ks = (idx >> 6) & 15;
        const int l  = idx & 63;
        const int row = l & 15, q = l >> 4;
        const size_t go = ((size_t)(gt * NH + j0 + row)) * NH + ks * 32 + q * 8;
        *(u32x4*)&Bsh0[gt][ks][l][0] = *(const u32x4*)(wb0  + go);
        *(u32x4*)&Bsh1[gt][ks][l][0] = *(const u32x4*)(wb1i + go);
    }
    // ---- one-time: wb1h fragments into 256 VGPRs/lane ----
    u32x4 whr[64];
    #pragma unroll
    for (int gt = 0; gt < 4; ++gt) {
        #pragma unroll
        for (int ks = 0; ks < 16; ++ks)
            whr[gt * 16 + ks] = *(const u32x4*)(
                wb1h + ((size_t)(gt * NH + j0 + ln15)) * NH + ks * 32 + quad * 8);
    }
    __syncthreads();

    // step-invariant scalars
    const float b0i = bsum0[jv],          b0f = bsum0[NH + jv];
    const float b0g = bsum0[2 * NH + jv], b0o = bsum0[3 * NH + jv];
    const float wxi = wih0f[jv],          wxf = wih0f[NH + jv];
    const float wxg = wih0f[2 * NH + jv], wxo = wih0f[3 * NH + jv];
    const float b1i = bsum1[jv],          b1f = bsum1[NH + jv];
    const float b1g = bsum1[2 * NH + jv], b1o = bsum1[3 * NH + jv];
    const float wl_ = wlinf[jv];
    const float bl_ = blinf[0];

    float c1r[4] = {0.f, 0.f, 0.f, 0.f};
    float c2r[4] = {0.f, 0.f, 0.f, 0.f};

    unsigned short* h1p[2] = { h1a, h1b };
    unsigned short* h2p[2] = { h2a, h2b };
    int* flagA = flags;                  // flagA[t]: h1(t) ready (t = 0..255)
    int* flagB = flags + 256 * 8 * 32;   // flagB[t]: h2(t) (+parts(t)) ready

    u32x4 rA1[8], rA2[8], rH2a[8], rH2b[8];

    // ---- prologue: h1(0) = f(x(0)) (h1(-1)=0 -> pure epilogue) ----
    {
        float xv[4];
        f32x4 b0 = {0.f, 0.f, 0.f, 0.f};
        f32x4 b1 = b0, b2 = b0, b3 = b0;
        #pragma unroll
        for (int r = 0; r < 4; ++r)
            xv[r] = xin[(size_t)(mb + r) * NT + 0];
        LSTM9_L0_EPI(h1p[1]);            // h1(0) lives in h1p[1]
        lstm9_drain();
        __syncthreads();
        if (tid == 0) lstm9_stI(flagA + (0 * 8 + g) * 32 + jt, 1);
    }

    // ---- main loop: ITER(t) = L1(t) + L0(t+1), t = 0..254 ----
    for (int t = 0; t < 255; ++t) {
        const unsigned short* h1rd = h1p[(t + 1) & 1];   // h1(t)
        unsigned short*       h1wr = h1p[t & 1];         // h1(t+1)
        const unsigned short* h2rd = h2p[t & 1];         // h2(t-1)
        unsigned short*       h2wr = h2p[(t + 1) & 1];   // h2(t)

        // top poll: h1(t) ready (+ h2(t-1)/WAR cert for t>=1)
        if (t == 0) lstm9_waitgrp(flagA + (0 * 8 + g) * 32);
        else        lstm9_waitgrp2(flagA + (t * 8 + g) * 32,
                                   flagB + ((t - 1) * 8 + g) * 32);

        // issue ALL 32 A-loads: h2(t-1) 16 + h1(t) 16
        #pragma unroll
        for (int ks = 0; ks < 8; ++ks)
            lstm9_ldA(rH2a[ks], h2rd + (size_t)rowA * NH + ks * 32 + quad * 8);
        #pragma unroll
        for (int ks = 0; ks < 8; ++ks)
            lstm9_ldA(rH2b[ks], h2rd + (size_t)rowA * NH + (8 + ks) * 32 + quad * 8);
        #pragma unroll
        for (int ks = 0; ks < 8; ++ks)
            lstm9_ldA(rA1[ks], h1rd + (size_t)rowA * NH + ks * 32 + quad * 8);
        #pragma unroll
        for (int ks = 0; ks < 8; ++ks)
            lstm9_ldA(rA2[ks], h1rd + (size_t)rowA * NH + (8 + ks) * 32 + quad * 8);

        // L1(t) vmcnt ladder
        f32x4 a0 = {0.f, 0.f, 0.f, 0.f};
        f32x4 a1 = a0, a2 = a0, a3 = a0;
        LSTM9_W8(24, rH2a[0], rH2a[1], rH2a[2], rH2a[3],
                     rH2a[4], rH2a[5], rH2a[6], rH2a[7]);
        #pragma unroll
        for (int ks = 0; ks < 8; ++ks) {
            const bf16x8 af = *(const bf16x8*)&rH2a[ks];
            a0 = __builtin_amdgcn_mfma_f32_16x16x32_bf16(af, WHR(0, ks), a0, 0, 0, 0);
            a1 = __builtin_amdgcn_mfma_f32_16x16x32_bf16(af, WHR(1, ks), a1, 0, 0, 0);
            a2 = __builtin_amdgcn_mfma_f32_16x16x32_bf16(af, WHR(2, ks), a2, 0, 0, 0);
            a3 = __builtin_amdgcn_mfma_f32_16x16x32_bf16(af, WHR(3, ks), a3, 0, 0, 0);
        }
        LSTM9_W8(16, rH2b[0], rH2b[1], rH2b[2], rH2b[3],
                     rH2b[4], rH2b[5], rH2b[6], rH2b[7]);
        #pragma unroll
        for (int ks = 0; ks < 8; ++ks) {
            const bf16x8 af = *(const bf16x8*)&rH2b[ks];
            a0 = __builtin_amdgcn_mfma_f32_16x16x32_bf16(af, WHR(0, 8 + ks), a0, 0, 0, 0);
            a1 = __builtin_amdgcn_mfma_f32_16x16x32_bf16(af, WHR(1, 8 + ks), a1, 0, 0, 0);
            a2 = __builtin_amdgcn_mfma_f32_16x16x32_bf16(af, WHR(2, 8 + ks), a2, 0, 0, 0);
            a3 = __builtin_amdgcn_mfma_f32_16x16x32_bf16(af, WHR(3, 8 + ks), a3, 0, 0, 0);
        }
        LSTM9_W8(8, rA1[0], rA1[1], rA1[2], rA1[3],
                    rA1[4], rA1[5], rA1[6], rA1[7]);
        #pragma unroll
        for (int ks = 0; ks < 8; ++ks) {
            const bf16x8 af = *(const bf16x8*)&rA1[ks];
            a0 = __builtin_amdgcn_mfma_f32_16x16x32_bf16(af, BFR1(0, ks), a0, 0, 0, 0);
            a1 = __builtin_amdgcn_mfma_f32_16x16x32_bf16(af, BFR1(1, ks), a1, 0, 0, 0);
            a2 = __builtin_amdgcn_mfma_f32_16x16x32_bf16(af, BFR1(2, ks), a2, 0, 0, 0);
            a3 = __builtin_amdgcn_mfma_f32_16x16x32_bf16(af, BFR1(3, ks), a3, 0, 0, 0);
        }
        LSTM9_W8(0, rA2[0], rA2[1], rA2[2], rA2[3],
                    rA2[4], rA2[5], rA2[6], rA2[7]);
        #pragma unroll
        for (int ks = 0; ks < 8; ++ks) {
            const bf16x8 af = *(const bf16x8*)&rA2[ks];
            a0 = __builtin_amdgcn_mfma_f32_16x16x32_bf16(af, BFR1(0, 8 + ks), a0, 0, 0, 0);
            a1 = __builtin_amdgcn_mfma_f32_16x16x32_bf16(af, BFR1(1, 8 + ks), a1, 0, 0, 0);
            a2 = __builtin_amdgcn_mfma_f32_16x16x32_bf16(af, BFR1(2, 8 + ks), a2, 0, 0, 0);
            a3 = __builtin_amdgcn_mfma_f32_16x16x32_bf16(af, BFR1(3, 8 + ks), a3, 0, 0, 0);
        }

        // L1(t) epilogue -> h2(t) (+ parts(t) in AR)
        float hv[4], cva[4];
        #pragma unroll
        for (int r = 0; r < 4; ++r) {
            const float gi = a0[r] + b1i;
            const float gf = a1[r] + b1f;
            const float gg = a2[r] + b1g;
            const float go = a3[r] + b1o;
            float cv = c2r[r];
            cv = lstm9_sig(gf) * cv + lstm9_sig(gi) * tanhf(gg);
            c2r[r] = cv;
            cva[r] = cv;
            hv[r] = lstm9_sig(go) * tanhf(cv);
            lstm9_stH(h2wr + (size_t)(mb + r) * NH + jv, lstm9_f2b(hv[r]));
        }

        f32x4 b0 = {0.f, 0.f, 0.f, 0.f};
        f32x4 b1 = b0, b2 = b0, b3 = b0;

        if (t < 127) {
            // ---- TF: L0(t+1) with x from input; ONE drain, both flags ----
            LSTM9_L0_MFMAS();            // overlaps h2 store flight
            float xv[4];
            #pragma unroll
            for (int r = 0; r < 4; ++r)
                xv[r] = xin[(size_t)(mb + r) * NT + (t + 1)];
            LSTM9_L0_EPI(h1wr);
            lstm9_drain();               // h2(t) + h1(t+1) stores acked
            __syncthreads();
            if (tid == 0) {
                lstm9_stI(flagB + (t * 8 + g) * 32 + jt, 1);
                lstm9_stI(flagA + ((t + 1) * 8 + g) * 32 + jt, 1);
            }
        } else {
            // ---- AR: parts(t) -> flagB(t) -> L0 MFMAs (hide skew) ->
            //      poll flagB(t) -> y -> L0 epi -> flagA(t+1) ----
            #pragma unroll
            for (int r = 0; r < 4; ++r)
                redsh[wv * 16 + quad * 4 + r][ln15] =
                    (t == 127 ? cva[r] : hv[r]) * wl_;   // y0-from-c2 quirk
            __syncthreads();
            if (tid < 64) {
                float s = 0.0f;
                #pragma unroll
                for (int j = 0; j < 16; ++j) s += redsh[tid][j];
                lstm9_stF(parts + (size_t)(t & 1) * NB * 32
                                + (size_t)(m0 + tid) * 32 + jt, s);
            }
            lstm9_drain();               // h2(t) + parts(t) acked
            __syncthreads();
            if (tid == 0) lstm9_stI(flagB + (t * 8 + g) * 32 + jt, 1);

            if (t < 254) LSTM9_L0_MFMAS();   // overlaps flagB flight + skew

            lstm9_waitgrp(flagB + (t * 8 + g) * 32);
            const float* pslot = parts + (size_t)(t & 1) * NB * 32;
            {
                const int row = tid >> 2, q = tid & 3;
                u32x4 v0, v1;
                lstm9_ldP(v0, pslot + (size_t)(m0 + row) * 32 + q * 8);
                lstm9_ldP(v1, pslot + (size_t)(m0 + row) * 32 + q * 8 + 4);
                LSTM9_WAIT2(v0, v1);
                const float* f0 = (const float*)&v0;
                const float* f1 = (const float*)&v1;
                redsh[row][q] = f0[0] + f0[1] + f0[2] + f0[3]
                              + f1[0] + f1[1] + f1[2] + f1[3];
            }
            __syncthreads();
            if (tid < 64) {
                const float y = bl_ + redsh[tid][0] + redsh[tid][1]
                                    + redsh[tid][2] + redsh[tid][3];
                ysh[tid] = y;
                if (jt == 0)
                    outf[(size_t)(m0 + tid) * NT + (t - 127)] = y;
            }
            __syncthreads();
            if (t == 254) break;         // last output published; done

            float xv[4];
            #pragma unroll
            for (int r = 0; r < 4; ++r)
                xv[r] = ysh[wv * 16 + quad * 4 + r];
            LSTM9_L0_EPI(h1wr);
            lstm9_drain();               // h1(t+1) stores acked
            __syncthreads();
            if (tid == 0) lstm9_stI(flagA + ((t + 1) * 8 + g) * 32 + jt, 1);
        }
    }
}

extern "C" void kernel_launch(void* const* d_in, const int* in_sizes, int n_in,
                              void* d_out, int out_size, void* d_ws, size_t ws_size,
                              hipStream_t stream)
{
    int base = 3;
    if (!(n_in > 3 && in_sizes[3] == 4 * NH)) {
        for (int i = 1; i + 9 < n_in; ++i)
            if (in_sizes[i] == 4 * NH) { base = i; break; }
    }
    const float* xin  = (const float*)d_in[0];
    const float* wih0 = (const float*)d_in[base + 0];
    const float* whh0 = (const float*)d_in[base + 1];
    const float* bih0 = (const float*)d_in[base + 2];
    const float* bhh0 = (const float*)d_in[base + 3];
    const float* wih1 = (const float*)d_in[base + 4];
    const float* whh1 = (const float*)d_in[base + 5];
    const float* bih1 = (const float*)d_in[base + 6];
    const float* bhh1 = (const float*)d_in[base + 7];
    const float* wlin = (const float*)d_in[base + 8];
    const float* blin = (const float*)d_in[base + 9];
    float* outf = (float*)d_out;

    // ws layout (~9 MB): bf16 weights | bf16 h ping-pong | fp32 bias |
    // y-partials | flags.
    const size_t NW = (size_t)4 * NH * NH;
    const size_t S  = (size_t)NB * NH;
    unsigned short* wb0  = (unsigned short*)d_ws;
    unsigned short* wb1i = wb0 + NW;
    unsigned short* wb1h = wb1i + NW;
    unsigned short* h1b0 = wb1h + NW;
    unsigned short* h1b1 = h1b0 + S;
    unsigned short* h2b0 = h1b1 + S;
    unsigned short* h2b1 = h2b0 + S;
    float* bsum0 = (float*)(h2b1 + S);
    float* bsum1 = bsum0 + 4 * NH;
    float* parts = bsum1 + 4 * NH;               // 2 slots x 512 m x 32 j
    int*   flags = (int*)(parts + 2 * NB * 32);  // flagA | flagB

    lstm9_mark<<<(NB * NT + 255) / 256, 256, 0, stream>>>(outf);
    lstm9_prep<<<1024, 256, 0, stream>>>(whh0, wih1, whh1, bih0, bhh0, bih1, bhh1,
                                         wb0, wb1i, wb1h, bsum0, bsum1,
                                         h1b0, flags);
    lstm9_persist<<<256, 256, 0, stream>>>(xin, outf, wb0, wb1i, wb1h,
                                           bsum0, bsum1, wih0, wlin, blin,
                                           h1b0, h1b1, h2b0, h2b1,
                                           parts, flags);
}